// Round 1
// baseline (5871.614 us; speedup 1.0000x reference)
//
#include <hip/hip_runtime.h>
#include <math.h>

#define BS 8
#define NQ 8192
#define NT 512
#define NTHR 512
#define CHUNKS (NQ / NTHR)

// f32 cost, FMA-contraction-free, bit-identical everywhere it is computed.
// Mirrors: dists = sqrt(dx*dx + dy*dy); C = 0.5f*dists + cls
__device__ __forceinline__ float cost_f32(float qx, float qy, float cl, float tx, float ty) {
    float dx = __fsub_rn(qx, tx);
    float dy = __fsub_rn(qy, ty);
    float d2 = __fadd_rn(__fmul_rn(dx, dx), __fmul_rn(dy, dy));
    float d  = __fsqrt_rn(d2);
    return __fadd_rn(__fmul_rn(0.5f, d), cl);
}

__global__ void cls_kernel(const float* __restrict__ logits, float* __restrict__ cls, int n) {
    int i = blockIdx.x * blockDim.x + threadIdx.x;
    if (i < n) {
        float x = logits[i];
        float s;
        if (x >= 0.0f) { float e = expf(-x); s = 1.0f / (1.0f + e); }
        else           { float e = expf(x);  s = e / (1.0f + e); }
        cls[i] = __fsub_rn(1.0f, s);
    }
}

// One block per (b, q): 512 threads each produce C[b][q][t].
__global__ void c_kernel(const float* __restrict__ pred_points,
                         const float* __restrict__ tgt_points,
                         const float* __restrict__ cls,
                         float* __restrict__ C) {
    int bq = blockIdx.x;          // b*NQ + q
    int b  = bq >> 13;            // NQ = 8192
    int t  = threadIdx.x;
    float qx = pred_points[bq * 2 + 0];
    float qy = pred_points[bq * 2 + 1];
    float cl = cls[bq];
    float tx = tgt_points[(b * NT + t) * 2 + 0];
    float ty = tgt_points[(b * NT + t) * 2 + 1];
    C[(size_t)bq * NT + t] = cost_f32(qx, qy, cl, tx, ty);
}

// Per-batch workspace: doubles first (alignment), then ints.
// u[NT] v[NQ] shortest[NQ] | path[NQ] remaining[NQ] SR[NT] col4row[NT] row4col[NQ]
#define WSB_BYTES (NT*8 + NQ*8 + NQ*8 + NQ*4 + NQ*4 + NT*4 + NT*4 + NQ*4)

__global__ __launch_bounds__(NTHR) void lsa_kernel(
    const float* __restrict__ pred_points,
    const float* __restrict__ tgt_points,
    const float* __restrict__ cls,
    float* __restrict__ out_rows,
    float* __restrict__ out_cols,
    char* __restrict__ ws) {
    const int b = blockIdx.x;
    const int tid = threadIdx.x;

    char* base = ws + (size_t)b * WSB_BYTES;
    double* u        = (double*)base;          // NT
    double* v        = u + NT;                 // NQ
    double* shortest = v + NQ;                 // NQ
    int* path      = (int*)(shortest + NQ);    // NQ
    int* remaining = path + NQ;                // NQ
    int* SR        = remaining + NQ;           // NT
    int* col4row   = SR + NT;                  // NT
    int* row4col   = col4row + NT;             // NQ

    // full re-init each call (ws is poisoned; determinism required)
    for (int c = tid; c < NQ; c += NTHR) { v[c] = 0.0; path[c] = -1; row4col[c] = -1; }
    for (int r = tid; r < NT; r += NTHR) { u[r] = 0.0; col4row[r] = -1; }

    __shared__ double s_pval[NTHR / 64];
    __shared__ int    s_pidx[NTHR / 64];
    __shared__ double s_minval;
    __shared__ int    s_i;
    __shared__ int    s_sink;
    __syncthreads();

    for (int cur_row = 0; cur_row < NT; ++cur_row) {
        for (int c = tid; c < NQ; c += NTHR) { remaining[c] = 1; shortest[c] = INFINITY; }
        for (int r = tid; r < NT; r += NTHR) SR[r] = 0;
        if (tid == 0) { s_minval = 0.0; s_i = cur_row; s_sink = -1; SR[cur_row] = 1; }
        __syncthreads();

        while (true) {
            const int    i    = s_i;
            const double minv = s_minval;
            const double ui   = u[i];
            const float  tx   = tgt_points[(b * NT + i) * 2 + 0];
            const float  ty   = tgt_points[(b * NT + i) * 2 + 1];

            double best = INFINITY;
            int bestc = NQ;
            // ascending column order per thread + strict < == np.argmin first-min tiebreak
            for (int ch = 0; ch < CHUNKS; ++ch) {
                int c = ch * NTHR + tid;
                if (remaining[c]) {
                    float qx = pred_points[(b * NQ + c) * 2 + 0];
                    float qy = pred_points[(b * NQ + c) * 2 + 1];
                    float cf = cost_f32(qx, qy, cls[b * NQ + c], tx, ty);
                    double rr = ((minv + (double)cf) - ui) - v[c];
                    double sh = shortest[c];
                    if (rr < sh) { shortest[c] = rr; path[c] = i; sh = rr; }
                    if (sh < best) { best = sh; bestc = c; }
                }
            }
            // wave (64-lane) reduce with index tie-break
            for (int off = 32; off > 0; off >>= 1) {
                double ov = __shfl_down(best, off, 64);
                int    oc = __shfl_down(bestc, off, 64);
                if (ov < best || (ov == best && oc < bestc)) { best = ov; bestc = oc; }
            }
            if ((tid & 63) == 0) { s_pval[tid >> 6] = best; s_pidx[tid >> 6] = bestc; }
            __syncthreads();
            if (tid == 0) {
                best = s_pval[0]; bestc = s_pidx[0];
                for (int w = 1; w < NTHR / 64; ++w) {
                    if (s_pval[w] < best || (s_pval[w] == best && s_pidx[w] < bestc)) {
                        best = s_pval[w]; bestc = s_pidx[w];
                    }
                }
                const int k = bestc;
                s_minval = best;
                remaining[k] = 0;
                const int rk = row4col[k];
                if (rk == -1) { s_sink = k; }
                else { s_i = rk; SR[rk] = 1; }
            }
            __syncthreads();
            if (s_sink != -1) break;
        }

        const double minv = s_minval;
        const int sink = s_sink;
        // dual updates (read pre-augment col4row; augmentation comes after barrier)
        for (int r = tid; r < NT; r += NTHR) {
            if (SR[r] && r != cur_row) u[r] += minv - shortest[col4row[r]];
        }
        if (tid == 0) u[cur_row] += minv;
        for (int c = tid; c < NQ; c += NTHR) {
            if (!remaining[c]) v[c] -= minv - shortest[c];
        }
        __syncthreads();
        if (tid == 0) {
            int j = sink;
            while (true) {
                int i = path[j];
                row4col[j] = i;
                int t = col4row[i];
                col4row[i] = j;
                j = t;
                if (i == cur_row) break;
            }
        }
        __syncthreads();
    }

    // row_ind = sorted(col4row), col_ind = argsort(col4row); values distinct -> rank by counting
    for (int r = tid; r < NT; r += NTHR) {
        int q = col4row[r];
        int rank = 0;
        for (int r2 = 0; r2 < NT; ++r2) rank += (col4row[r2] < q) ? 1 : 0;
        out_rows[b * NT + rank] = (float)q;
        out_cols[b * NT + rank] = (float)r;
    }
}

extern "C" void kernel_launch(void* const* d_in, const int* in_sizes, int n_in,
                              void* d_out, int out_size, void* d_ws, size_t ws_size,
                              hipStream_t stream) {
    const float* logits = (const float*)d_in[0];  // (8, 8192, 1)
    const float* pred   = (const float*)d_in[1];  // (8, 8192, 2)
    const float* tgt    = (const float*)d_in[2];  // (8, 512, 2)

    float* out  = (float*)d_out;
    float* C    = out;                                   // BS*NQ*NT
    float* orow = out + (size_t)BS * NQ * NT;            // BS*NT
    float* ocol = orow + (size_t)BS * NT;                // BS*NT

    float* cls  = (float*)d_ws;                          // BS*NQ floats
    char*  lsaws = (char*)d_ws + ((size_t)BS * NQ * sizeof(float) + 255 & ~(size_t)255);

    cls_kernel<<<(BS * NQ + 255) / 256, 256, 0, stream>>>(logits, cls, BS * NQ);
    c_kernel<<<BS * NQ, NT, 0, stream>>>(pred, tgt, cls, C);
    lsa_kernel<<<BS, NTHR, 0, stream>>>(pred, tgt, cls, orow, ocol, (char*)lsaws);
}

// Round 2
// 1980.607 us; speedup vs baseline: 2.9646x; 2.9646x over previous
//
#include <hip/hip_runtime.h>
#include <math.h>

#define BS 8
#define NQ 8192
#define NT 512
#define NTHR 1024
#define CHUNKS (NQ / NTHR)   // 8 columns per thread
#define NW (NTHR / 64)       // 16 waves
#define MAXL (NT + 1)        // max SAP iterations per row

// f32 cost, FMA-contraction-free, bit-identical everywhere it is computed.
// Mirrors: dists = sqrt(dx*dx + dy*dy); C = 0.5f*dists + cls
__device__ __forceinline__ float cost_f32(float qx, float qy, float cl, float tx, float ty) {
    float dx = __fsub_rn(qx, tx);
    float dy = __fsub_rn(qy, ty);
    float d2 = __fadd_rn(__fmul_rn(dx, dx), __fmul_rn(dy, dy));
    float d  = __fsqrt_rn(d2);
    return __fadd_rn(__fmul_rn(0.5f, d), cl);
}

__global__ void cls_kernel(const float* __restrict__ logits, float* __restrict__ cls, int n) {
    int i = blockIdx.x * blockDim.x + threadIdx.x;
    if (i < n) {
        float x = logits[i];
        float s;
        if (x >= 0.0f) { float e = expf(-x); s = 1.0f / (1.0f + e); }
        else           { float e = expf(x);  s = e / (1.0f + e); }
        cls[i] = __fsub_rn(1.0f, s);
    }
}

// One block per (b, q): 512 threads each produce C[b][q][t].
__global__ void c_kernel(const float* __restrict__ pred_points,
                         const float* __restrict__ tgt_points,
                         const float* __restrict__ cls,
                         float* __restrict__ C) {
    int bq = blockIdx.x;          // b*NQ + q
    int b  = bq >> 13;            // NQ = 8192
    int t  = threadIdx.x;
    float qx = pred_points[bq * 2 + 0];
    float qy = pred_points[bq * 2 + 1];
    float cl = cls[bq];
    float tx = tgt_points[(b * NT + t) * 2 + 0];
    float ty = tgt_points[(b * NT + t) * 2 + 1];
    C[(size_t)bq * NT + t] = cost_f32(qx, qy, cl, tx, ty);
}

// Register/LDS-resident shortest-augmenting-path LSA, one block per batch.
// Thread `tid` owns columns c = j*NTHR + tid, j in [0, CHUNKS).
__global__ __launch_bounds__(NTHR) void lsa_kernel(
    const float* __restrict__ pred_points,
    const float* __restrict__ tgt_points,
    const float* __restrict__ cls,
    float* __restrict__ out_rows,
    float* __restrict__ out_cols) {
    const int b = blockIdx.x;
    const int tid = threadIdx.x;

    __shared__ short  path_s[NQ];      // 16 KB
    __shared__ short  row4col_s[NQ];   // 16 KB
    __shared__ short  col4row_s[NT];   // 1 KB
    __shared__ double u_s[NT];         // 4 KB
    __shared__ float  tg[NT * 2];      // 4 KB
    __shared__ double l_minv[MAXL];    // per-iteration removal list
    __shared__ short  l_k[MAXL];
    __shared__ short  l_r[MAXL];
    __shared__ double s_pval[NW];
    __shared__ int    s_pidx[NW];
    __shared__ double s_minval;
    __shared__ int    s_i, s_sink, s_k, s_len;

    for (int c = tid; c < NQ; c += NTHR) row4col_s[c] = -1;
    for (int r = tid; r < NT; r += NTHR) { col4row_s[r] = -1; u_s[r] = 0.0; }
    for (int t = tid; t < NT * 2; t += NTHR) tg[t] = tgt_points[b * NT * 2 + t];

    // per-thread column state in registers
    float  qx[CHUNKS], qy[CHUNKS], cl[CHUNKS];
    double v_r[CHUNKS], sh_r[CHUNKS];
    for (int j = 0; j < CHUNKS; ++j) {
        int c = j * NTHR + tid;
        qx[j] = pred_points[(b * NQ + c) * 2 + 0];
        qy[j] = pred_points[(b * NQ + c) * 2 + 1];
        cl[j] = cls[b * NQ + c];
        v_r[j] = 0.0;
    }
    __syncthreads();

    for (int cur_row = 0; cur_row < NT; ++cur_row) {
        unsigned rem = (1u << CHUNKS) - 1;
        for (int j = 0; j < CHUNKS; ++j) sh_r[j] = (double)INFINITY;
        if (tid == 0) { s_minval = 0.0; s_i = cur_row; s_sink = -1; s_k = -1; s_len = 0; }
        __syncthreads();

        for (;;) {
            {   // clear the bit of the column removed last iteration (owner only)
                int kk = s_k;
                if (kk >= 0 && (kk & (NTHR - 1)) == tid) rem &= ~(1u << (kk >> 10));
            }
            const int    i    = s_i;
            const double minv = s_minval;
            const double ui   = u_s[i];
            const float  tx   = tg[i * 2 + 0];
            const float  ty   = tg[i * 2 + 1];

            double best = (double)INFINITY;
            int bestc = NQ;
            // ascending column order + strict < == np.argmin first-min tiebreak
            for (int j = 0; j < CHUNKS; ++j) {
                if (rem & (1u << j)) {
                    float cf = cost_f32(qx[j], qy[j], cl[j], tx, ty);
                    double rr = ((minv + (double)cf) - ui) - v_r[j];
                    double sh = sh_r[j];
                    if (rr < sh) { sh_r[j] = rr; sh = rr; path_s[j * NTHR + tid] = (short)i; }
                    if (sh < best) { best = sh; bestc = j * NTHR + tid; }
                }
            }
            // wave (64-lane) reduce with index tie-break
            for (int off = 32; off > 0; off >>= 1) {
                double ov = __shfl_down(best, off, 64);
                int    oc = __shfl_down(bestc, off, 64);
                if (ov < best || (ov == best && oc < bestc)) { best = ov; bestc = oc; }
            }
            if ((tid & 63) == 0) { s_pval[tid >> 6] = best; s_pidx[tid >> 6] = bestc; }
            __syncthreads();
            if (tid < 64) {
                double bv = (tid < NW) ? s_pval[tid] : (double)INFINITY;
                int    bc = (tid < NW) ? s_pidx[tid] : NQ;
                for (int off = 8; off > 0; off >>= 1) {
                    double ov = __shfl_down(bv, off, 64);
                    int    oc = __shfl_down(bc, off, 64);
                    if (ov < bv || (ov == bv && oc < bc)) { bv = ov; bc = oc; }
                }
                if (tid == 0) {
                    const int k = bc;
                    s_minval = bv;
                    s_k = k;
                    const int rk = row4col_s[k];
                    const int len = s_len;
                    l_k[len] = (short)k; l_minv[len] = bv; l_r[len] = (short)rk;
                    s_len = len + 1;
                    if (rk == -1) s_sink = k; else s_i = rk;
                }
            }
            __syncthreads();
            if (s_sink != -1) break;
        }

        const double minv = s_minval;
        const int L = s_len;
        // u duals: each list entry's rk is a distinct SR row; shortest[col4row[rk]] == l_minv[e]
        for (int e = tid; e < L; e += NTHR) {
            int rk = l_r[e];
            if (rk != -1) u_s[rk] += minv - l_minv[e];
        }
        if (tid == 0) u_s[cur_row] += minv;
        // v duals: removed columns only; shortest[k] == l_minv[e]; owner thread updates its register
        for (int e = 0; e < L; ++e) {
            int k = l_k[e];
            if ((k & (NTHR - 1)) == tid) v_r[k >> 10] -= (minv - l_minv[e]);
        }
        __syncthreads();
        if (tid == 0) {
            int j = s_sink;
            for (;;) {
                int i = path_s[j];
                row4col_s[j] = (short)i;
                int t = col4row_s[i];
                col4row_s[i] = (short)j;
                j = t;
                if (i == cur_row) break;
            }
        }
        __syncthreads();
    }

    // row_ind = sorted(col4row), col_ind = argsort(col4row); values distinct -> rank by counting
    for (int r = tid; r < NT; r += NTHR) {
        int q = col4row_s[r];
        int rank = 0;
        for (int r2 = 0; r2 < NT; ++r2) rank += (col4row_s[r2] < q) ? 1 : 0;
        out_rows[b * NT + rank] = (float)q;
        out_cols[b * NT + rank] = (float)r;
    }
}

extern "C" void kernel_launch(void* const* d_in, const int* in_sizes, int n_in,
                              void* d_out, int out_size, void* d_ws, size_t ws_size,
                              hipStream_t stream) {
    const float* logits = (const float*)d_in[0];  // (8, 8192, 1)
    const float* pred   = (const float*)d_in[1];  // (8, 8192, 2)
    const float* tgt    = (const float*)d_in[2];  // (8, 512, 2)

    float* out  = (float*)d_out;
    float* C    = out;                                   // BS*NQ*NT
    float* orow = out + (size_t)BS * NQ * NT;            // BS*NT
    float* ocol = orow + (size_t)BS * NT;                // BS*NT

    float* cls  = (float*)d_ws;                          // BS*NQ floats

    cls_kernel<<<(BS * NQ + 255) / 256, 256, 0, stream>>>(logits, cls, BS * NQ);
    c_kernel<<<BS * NQ, NT, 0, stream>>>(pred, tgt, cls, C);
    lsa_kernel<<<BS, NTHR, 0, stream>>>(pred, tgt, cls, orow, ocol);
}

// Round 3
// 1929.918 us; speedup vs baseline: 3.0424x; 1.0263x over previous
//
#include <hip/hip_runtime.h>
#include <math.h>

#define BS 8
#define NQ 8192
#define NT 512
#define NTHR 512
#define CHUNKS 16            // NQ / NTHR columns per thread
#define NW (NTHR / 64)       // 8 waves
#define MAXL (NT + 1)

#define DINF (__builtin_inf())

// f32 cost, FMA-contraction-free, bit-identical everywhere it is computed.
// Mirrors: dists = sqrt(dx*dx + dy*dy); C = 0.5f*dists + cls
__device__ __forceinline__ float cost_f32(float qx, float qy, float cl, float tx, float ty) {
    float dx = __fsub_rn(qx, tx);
    float dy = __fsub_rn(qy, ty);
    float d2 = __fadd_rn(__fmul_rn(dx, dx), __fmul_rn(dy, dy));
    float d  = __fsqrt_rn(d2);
    return __fadd_rn(__fmul_rn(0.5f, d), cl);
}

__global__ void cls_kernel(const float* __restrict__ logits, float* __restrict__ cls, int n) {
    int i = blockIdx.x * blockDim.x + threadIdx.x;
    if (i < n) {
        float x = logits[i];
        float s;
        if (x >= 0.0f) { float e = expf(-x); s = 1.0f / (1.0f + e); }
        else           { float e = expf(x);  s = e / (1.0f + e); }
        cls[i] = __fsub_rn(1.0f, s);
    }
}

// One block per (b, q): 512 threads each produce C[b][q][t].
__global__ void c_kernel(const float* __restrict__ pred_points,
                         const float* __restrict__ tgt_points,
                         const float* __restrict__ cls,
                         float* __restrict__ C) {
    int bq = blockIdx.x;          // b*NQ + q
    int b  = bq >> 13;            // NQ = 8192
    int t  = threadIdx.x;
    float qx = pred_points[bq * 2 + 0];
    float qy = pred_points[bq * 2 + 1];
    float cl = cls[bq];
    float tx = tgt_points[(b * NT + t) * 2 + 0];
    float ty = tgt_points[(b * NT + t) * 2 + 1];
    C[(size_t)bq * NT + t] = cost_f32(qx, qy, cl, tx, ty);
}

// Register-resident shortest-augmenting-path LSA, one block per batch.
// Thread `tid` owns columns c = j*NTHR + tid, j in [0, CHUNKS).
// Removed columns are made inert by vv=-inf (rr=+inf) and sh=+inf; their true
// v is saved in l_v and restored (with the dual update) at end of Dijkstra.
__global__ __launch_bounds__(NTHR, 2) void lsa_kernel(
    const float* __restrict__ pred_points,
    const float* __restrict__ tgt_points,
    const float* __restrict__ cls,
    float* __restrict__ out_rows,
    float* __restrict__ out_cols) {
    const int b = blockIdx.x;
    const int tid = threadIdx.x;

    __shared__ short  path_s[NQ];      // 16 KB
    __shared__ short  row4col_s[NQ];   // 16 KB
    __shared__ short  col4row_s[NT];   // 1 KB
    __shared__ double u_s[NT];         // 4 KB
    __shared__ float  tg[NT * 2];      // 4 KB
    __shared__ double l_minv[MAXL];    // removal list (per Dijkstra)
    __shared__ double l_v[MAXL];       // true v of removed column at removal
    __shared__ short  l_k[MAXL];
    __shared__ short  l_r[MAXL];
    __shared__ double p_val[2][NW];    // double-buffered wave partials
    __shared__ int    p_idx[2][NW];

    for (int c = tid; c < NQ; c += NTHR) row4col_s[c] = -1;
    for (int r = tid; r < NT; r += NTHR) { col4row_s[r] = -1; u_s[r] = 0.0; }
    for (int t = tid; t < NT * 2; t += NTHR) tg[t] = tgt_points[b * NT * 2 + t];

    // per-thread column state in registers (all indices compile-time)
    float  qx[CHUNKS], qy[CHUNKS], cl[CHUNKS];
    double vv[CHUNKS], sh[CHUNKS];
#pragma unroll
    for (int j = 0; j < CHUNKS; ++j) {
        int c = j * NTHR + tid;
        qx[j] = pred_points[(b * NQ + c) * 2 + 0];
        qy[j] = pred_points[(b * NQ + c) * 2 + 1];
        cl[j] = cls[b * NQ + c];
        vv[j] = 0.0;
    }
    __syncthreads();

    for (int cur_row = 0; cur_row < NT; ++cur_row) {
#pragma unroll
        for (int j = 0; j < CHUNKS; ++j) sh[j] = DINF;
        int    i    = cur_row;
        double minv = 0.0;
        int    len  = 0;
        int    sink = -1;

        for (;;) {
            const double w  = minv - u_s[i];
            const float  tx = tg[i * 2 + 0];
            const float  ty = tg[i * 2 + 1];

            double best = DINF;
            int bestc = NQ;
#pragma unroll
            for (int j = 0; j < CHUNKS; ++j) {
                float  cf = cost_f32(qx[j], qy[j], cl[j], tx, ty);
                double rr = (w + (double)cf) - vv[j];
                if (rr < sh[j]) { sh[j] = rr; path_s[j * NTHR + tid] = (short)i; }
                if (sh[j] < best) { best = sh[j]; bestc = j * NTHR + tid; }
            }
            // wave (64-lane) reduce with index tie-break
            for (int off = 32; off > 0; off >>= 1) {
                double ov = __shfl_down(best, off, 64);
                int    oc = __shfl_down(bestc, off, 64);
                if (ov < best || (ov == best && oc < bestc)) { best = ov; bestc = oc; }
            }
            const int par = len & 1;
            if ((tid & 63) == 0) { p_val[par][tid >> 6] = best; p_idx[par][tid >> 6] = bestc; }
            __syncthreads();
            // redundant cross-wave reduce: every lane gets (minv, k)
            double bv = p_val[par][tid & (NW - 1)];
            int    bc = p_idx[par][tid & (NW - 1)];
            for (int m = NW >> 1; m > 0; m >>= 1) {
                double ov = __shfl_xor(bv, m, 64);
                int    oc = __shfl_xor(bc, m, 64);
                if (ov < bv || (ov == bv && oc < bc)) { bv = ov; bc = oc; }
            }
            minv = bv;
            const int k  = bc;
            const int rk = row4col_s[k];
            if ((k & (NTHR - 1)) == tid) {   // owner neutralizes its column
                const int jj = k >> 9;       // log2(NTHR)
#pragma unroll
                for (int j = 0; j < CHUNKS; ++j)
                    if (j == jj) { l_v[len] = vv[j]; vv[j] = -DINF; sh[j] = DINF; }
            }
            if (tid == 0) { l_k[len] = (short)k; l_minv[len] = bv; l_r[len] = (short)rk; }
            ++len;
            if (rk < 0) { sink = k; break; }
            i = rk;
        }
        __syncthreads();   // l_* / path_s writes visible to everyone

        const int L = len;
        // u duals: distinct SR rows; shortest[col4row[r]] == l_minv[e]
        for (int e = tid; e < L; e += NTHR) {
            int rk2 = l_r[e];
            if (rk2 >= 0) u_s[rk2] += minv - l_minv[e];
        }
        if (tid == 0) u_s[cur_row] += minv;
        // v duals + restore (owner thread only; unrolled for static reg index)
        for (int e = 0; e < L; ++e) {
            int k2 = l_k[e];
            if ((k2 & (NTHR - 1)) == tid) {
                const int jj = k2 >> 9;
                double nv = l_v[e] - (minv - l_minv[e]);
#pragma unroll
                for (int j = 0; j < CHUNKS; ++j)
                    if (j == jj) vv[j] = nv;
            }
        }
        if (tid == 0) {   // augment along the alternating path
            int j = sink;
            for (;;) {
                int ii = path_s[j];
                row4col_s[j] = (short)ii;
                int t = col4row_s[ii];
                col4row_s[ii] = (short)j;
                j = t;
                if (ii == cur_row) break;
            }
        }
        __syncthreads();
    }

    // row_ind = sorted(col4row), col_ind = argsort(col4row); values distinct
    for (int r = tid; r < NT; r += NTHR) {
        int q = col4row_s[r];
        int rank = 0;
        for (int r2 = 0; r2 < NT; ++r2) rank += (col4row_s[r2] < q) ? 1 : 0;
        out_rows[b * NT + rank] = (float)q;
        out_cols[b * NT + rank] = (float)r;
    }
}

extern "C" void kernel_launch(void* const* d_in, const int* in_sizes, int n_in,
                              void* d_out, int out_size, void* d_ws, size_t ws_size,
                              hipStream_t stream) {
    const float* logits = (const float*)d_in[0];  // (8, 8192, 1)
    const float* pred   = (const float*)d_in[1];  // (8, 8192, 2)
    const float* tgt    = (const float*)d_in[2];  // (8, 512, 2)

    float* out  = (float*)d_out;
    float* C    = out;                                   // BS*NQ*NT
    float* orow = out + (size_t)BS * NQ * NT;            // BS*NT
    float* ocol = orow + (size_t)BS * NT;                // BS*NT

    float* cls  = (float*)d_ws;                          // BS*NQ floats

    cls_kernel<<<(BS * NQ + 255) / 256, 256, 0, stream>>>(logits, cls, BS * NQ);
    c_kernel<<<BS * NQ, NT, 0, stream>>>(pred, tgt, cls, C);
    lsa_kernel<<<BS, NTHR, 0, stream>>>(pred, tgt, cls, orow, ocol);
}

// Round 4
// 310.504 us; speedup vs baseline: 18.9100x; 6.2154x over previous
//
#include <hip/hip_runtime.h>
#include <math.h>

#define BS 8
#define NQ 8192
#define NT 512
#define NTHR 512
#define CHUNKS 16            // NQ / NTHR columns per thread
#define NW (NTHR / 64)       // 8 waves
#define MAXL (NT + 1)

#define DINF (__builtin_inf())

// f32 cost, FMA-contraction-free, bit-identical everywhere it is computed.
// Mirrors: dists = sqrt(dx*dx + dy*dy); C = 0.5f*dists + cls
__device__ __forceinline__ float cost_f32(float qx, float qy, float cl, float tx, float ty) {
    float dx = __fsub_rn(qx, tx);
    float dy = __fsub_rn(qy, ty);
    float d2 = __fadd_rn(__fmul_rn(dx, dx), __fmul_rn(dy, dy));
    float d  = __fsqrt_rn(d2);
    return __fadd_rn(__fmul_rn(0.5f, d), cl);
}

__global__ void cls_kernel(const float* __restrict__ logits, float* __restrict__ cls, int n) {
    int i = blockIdx.x * blockDim.x + threadIdx.x;
    if (i < n) {
        float x = logits[i];
        float s;
        if (x >= 0.0f) { float e = expf(-x); s = 1.0f / (1.0f + e); }
        else           { float e = expf(x);  s = e / (1.0f + e); }
        cls[i] = __fsub_rn(1.0f, s);
    }
}

// One block per (b, q): 512 threads each produce C[b][q][t].
__global__ void c_kernel(const float* __restrict__ pred_points,
                         const float* __restrict__ tgt_points,
                         const float* __restrict__ cls,
                         float* __restrict__ C) {
    int bq = blockIdx.x;          // b*NQ + q
    int b  = bq >> 13;            // NQ = 8192
    int t  = threadIdx.x;
    float qx = pred_points[bq * 2 + 0];
    float qy = pred_points[bq * 2 + 1];
    float cl = cls[bq];
    float tx = tgt_points[(b * NT + t) * 2 + 0];
    float ty = tgt_points[(b * NT + t) * 2 + 1];
    C[(size_t)bq * NT + t] = cost_f32(qx, qy, cl, tx, ty);
}

// One wave per (b, target-row): argmin over 8192 columns of the f32 cost.
// u0 = min value (== scipy's u[i] after a trivial one-step Dijkstra),
// jm = argmin with lowest-index tie-break (== np.argmin).
__global__ __launch_bounds__(256) void rowmin_kernel(
    const float* __restrict__ pred_points,
    const float* __restrict__ tgt_points,
    const float* __restrict__ cls,
    float* __restrict__ u0, int* __restrict__ jm) {
    const int wid  = blockIdx.x * 4 + (threadIdx.x >> 6);   // 4096 waves
    const int lane = threadIdx.x & 63;
    const int b = wid >> 9;
    const int i = wid & (NT - 1);
    const float tx = tgt_points[(b * NT + i) * 2 + 0];
    const float ty = tgt_points[(b * NT + i) * 2 + 1];
    const float2* p2 = (const float2*)pred_points;

    float best = DINF;
    int bestc = NQ;
    for (int k = 0; k < NQ / 64; ++k) {
        int c = k * 64 + lane;
        float2 q = p2[b * NQ + c];
        float cf = cost_f32(q.x, q.y, cls[b * NQ + c], tx, ty);
        if (cf < best) { best = cf; bestc = c; }   // ascending c -> first-min
    }
    for (int off = 32; off > 0; off >>= 1) {
        float ov = __shfl_down(best, off, 64);
        int   oc = __shfl_down(bestc, off, 64);
        if (ov < best || (ov == best && oc < bestc)) { best = ov; bestc = oc; }
    }
    if (lane == 0) { u0[b * NT + i] = best; jm[b * NT + i] = bestc; }
}

// Register-resident SAP LSA with JV-style row-reduction warm start.
// Thread `tid` owns columns c = j*NTHR + tid. Removed columns are made inert
// (vv=-inf -> rr=+inf, sh=+inf); true v saved in l_v, restored with duals.
__global__ __launch_bounds__(NTHR, 2) void lsa_kernel(
    const float* __restrict__ pred_points,
    const float* __restrict__ tgt_points,
    const float* __restrict__ cls,
    const float* __restrict__ u0,
    const int* __restrict__ jm,
    float* __restrict__ out_rows,
    float* __restrict__ out_cols) {
    const int b = blockIdx.x;
    const int tid = threadIdx.x;

    __shared__ short  path_s[NQ];      // 16 KB
    __shared__ short  row4col_s[NQ];   // 16 KB
    __shared__ short  col4row_s[NT];   // 1 KB
    __shared__ double u_s[NT];         // 4 KB
    __shared__ float  tg[NT * 2];      // 4 KB
    __shared__ short  jm_s[NT];        // 1 KB
    __shared__ short  defer_s[NT];     // 1 KB
    __shared__ int    s_ndefer;
    __shared__ double l_minv[MAXL];    // removal list (per Dijkstra)
    __shared__ double l_v[MAXL];       // true v of removed column at removal
    __shared__ short  l_k[MAXL];
    __shared__ short  l_r[MAXL];
    __shared__ double p_val[2][NW];    // double-buffered wave partials
    __shared__ int    p_idx[2][NW];

    for (int c = tid; c < NQ; c += NTHR) row4col_s[c] = -1;
    for (int r = tid; r < NT; r += NTHR) {
        col4row_s[r] = -1;
        u_s[r] = (double)u0[b * NT + r];
        jm_s[r] = (short)jm[b * NT + r];
    }
    for (int t = tid; t < NT * 2; t += NTHR) tg[t] = tgt_points[b * NT * 2 + t];

    // per-thread column state in registers (all indices compile-time)
    float  qx[CHUNKS], qy[CHUNKS], cl[CHUNKS];
    double vv[CHUNKS], sh[CHUNKS];
#pragma unroll
    for (int j = 0; j < CHUNKS; ++j) {
        int c = j * NTHR + tid;
        qx[j] = pred_points[(b * NQ + c) * 2 + 0];
        qy[j] = pred_points[(b * NQ + c) * 2 + 1];
        cl[j] = cls[b * NQ + c];
        vv[j] = 0.0;
    }
    __syncthreads();

    // Greedy assignment on zero-reduced-cost arcs, ascending row order
    // (lowest row wins a contested column == scipy's processing order).
    if (tid == 0) {
        int nd = 0;
        for (int i = 0; i < NT; ++i) {
            int j = jm_s[i];
            if (row4col_s[j] < 0) { row4col_s[j] = (short)i; col4row_s[i] = (short)j; }
            else defer_s[nd++] = (short)i;
        }
        s_ndefer = nd;
    }
    __syncthreads();
    const int ND = s_ndefer;

    for (int di = 0; di < ND; ++di) {
        const int cur_row = defer_s[di];
#pragma unroll
        for (int j = 0; j < CHUNKS; ++j) sh[j] = DINF;
        int    i    = cur_row;
        double minv = 0.0;
        int    len  = 0;
        int    sink = -1;

        for (;;) {
            const double w  = minv - u_s[i];
            const float  tx = tg[i * 2 + 0];
            const float  ty = tg[i * 2 + 1];

            double best = DINF;
            int bestc = NQ;
#pragma unroll
            for (int j = 0; j < CHUNKS; ++j) {
                float  cf = cost_f32(qx[j], qy[j], cl[j], tx, ty);
                double rr = (w + (double)cf) - vv[j];
                if (rr < sh[j]) { sh[j] = rr; path_s[j * NTHR + tid] = (short)i; }
                if (sh[j] < best) { best = sh[j]; bestc = j * NTHR + tid; }
            }
            // wave (64-lane) reduce with index tie-break
            for (int off = 32; off > 0; off >>= 1) {
                double ov = __shfl_down(best, off, 64);
                int    oc = __shfl_down(bestc, off, 64);
                if (ov < best || (ov == best && oc < bestc)) { best = ov; bestc = oc; }
            }
            const int par = len & 1;
            if ((tid & 63) == 0) { p_val[par][tid >> 6] = best; p_idx[par][tid >> 6] = bestc; }
            __syncthreads();
            // redundant cross-wave reduce: every lane gets (minv, k)
            double bv = p_val[par][tid & (NW - 1)];
            int    bc = p_idx[par][tid & (NW - 1)];
            for (int m = NW >> 1; m > 0; m >>= 1) {
                double ov = __shfl_xor(bv, m, 64);
                int    oc = __shfl_xor(bc, m, 64);
                if (ov < bv || (ov == bv && oc < bc)) { bv = ov; bc = oc; }
            }
            minv = bv;
            const int k  = bc;
            const int rk = row4col_s[k];
            if ((k & (NTHR - 1)) == tid) {   // owner neutralizes its column
                const int jj = k >> 9;       // log2(NTHR)
#pragma unroll
                for (int j = 0; j < CHUNKS; ++j)
                    if (j == jj) { l_v[len] = vv[j]; vv[j] = -DINF; sh[j] = DINF; }
            }
            if (tid == 0) { l_k[len] = (short)k; l_minv[len] = bv; l_r[len] = (short)rk; }
            ++len;
            if (rk < 0) { sink = k; break; }
            i = rk;
        }
        __syncthreads();   // l_* / path_s writes visible to everyone

        const int L = len;
        // u duals: distinct SR rows; shortest[col4row[r]] == l_minv[e]
        for (int e = tid; e < L; e += NTHR) {
            int rk2 = l_r[e];
            if (rk2 >= 0) u_s[rk2] += minv - l_minv[e];
        }
        if (tid == 0) u_s[cur_row] += minv;
        // v duals + restore (owner thread only; unrolled for static reg index)
        for (int e = 0; e < L; ++e) {
            int k2 = l_k[e];
            if ((k2 & (NTHR - 1)) == tid) {
                const int jj = k2 >> 9;
                double nv = l_v[e] - (minv - l_minv[e]);
#pragma unroll
                for (int j = 0; j < CHUNKS; ++j)
                    if (j == jj) vv[j] = nv;
            }
        }
        if (tid == 0) {   // augment along the alternating path
            int j = sink;
            for (;;) {
                int ii = path_s[j];
                row4col_s[j] = (short)ii;
                int t = col4row_s[ii];
                col4row_s[ii] = (short)j;
                j = t;
                if (ii == cur_row) break;
            }
        }
        __syncthreads();
    }

    // row_ind = sorted(col4row), col_ind = argsort(col4row); values distinct
    for (int r = tid; r < NT; r += NTHR) {
        int q = col4row_s[r];
        int rank = 0;
        for (int r2 = 0; r2 < NT; ++r2) rank += (col4row_s[r2] < q) ? 1 : 0;
        out_rows[b * NT + rank] = (float)q;
        out_cols[b * NT + rank] = (float)r;
    }
}

extern "C" void kernel_launch(void* const* d_in, const int* in_sizes, int n_in,
                              void* d_out, int out_size, void* d_ws, size_t ws_size,
                              hipStream_t stream) {
    const float* logits = (const float*)d_in[0];  // (8, 8192, 1)
    const float* pred   = (const float*)d_in[1];  // (8, 8192, 2)
    const float* tgt    = (const float*)d_in[2];  // (8, 512, 2)

    float* out  = (float*)d_out;
    float* C    = out;                                   // BS*NQ*NT
    float* orow = out + (size_t)BS * NQ * NT;            // BS*NT
    float* ocol = orow + (size_t)BS * NT;                // BS*NT

    float* cls = (float*)d_ws;                           // BS*NQ floats
    float* u0  = cls + BS * NQ;                          // BS*NT floats
    int*   jmn = (int*)(u0 + BS * NT);                   // BS*NT ints

    cls_kernel<<<(BS * NQ + 255) / 256, 256, 0, stream>>>(logits, cls, BS * NQ);
    c_kernel<<<BS * NQ, NT, 0, stream>>>(pred, tgt, cls, C);
    rowmin_kernel<<<BS * NT / 4, 256, 0, stream>>>(pred, tgt, cls, u0, jmn);
    lsa_kernel<<<BS, NTHR, 0, stream>>>(pred, tgt, cls, u0, jmn, orow, ocol);
}

// Round 5
// 301.294 us; speedup vs baseline: 19.4880x; 1.0306x over previous
//
#include <hip/hip_runtime.h>
#include <math.h>

#define BS 8
#define NQ 8192
#define NT 512
#define NTHR 512
#define CHUNKS 16            // NQ / NTHR columns per thread
#define NW (NTHR / 64)       // 8 waves
#define MAXL (NT + 1)
#define QCAP 2560            // queue capacity (shorts)
#define ARR_CAP 2048         // max ARR steps (termination guarantee)
#define KMASK 0xFFFFFFFFFFFFE000ull

#define DINF (__builtin_inf())

// f32 cost, FMA-contraction-free, bit-identical everywhere it is computed.
// Mirrors: dists = sqrt(dx*dx + dy*dy); C = 0.5f*dists + cls
__device__ __forceinline__ float cost_f32(float qx, float qy, float cl, float tx, float ty) {
    float dx = __fsub_rn(qx, tx);
    float dy = __fsub_rn(qy, ty);
    float d2 = __fadd_rn(__fmul_rn(dx, dx), __fmul_rn(dy, dy));
    float d  = __fsqrt_rn(d2);
    return __fadd_rn(__fmul_rn(0.5f, d), cl);
}

// packed (value,idx) key: non-negative doubles compare correctly as u64 bits;
// low 13 bits replaced by column idx -> min == (min value, lowest idx).
__device__ __forceinline__ unsigned long long pack_key(double v, int idx) {
    double c = fmax(v, 0.0);   // clamp 1e-12 dual fuzz; exact for positives
    return (((unsigned long long)__double_as_longlong(c)) & KMASK)
         | (unsigned long long)((unsigned)idx & 0x1FFFu);
}
__device__ __forceinline__ double key_val(unsigned long long k) {
    return __longlong_as_double((long long)(k & KMASK));
}

__global__ void cls_kernel(const float* __restrict__ logits, float* __restrict__ cls, int n) {
    int i = blockIdx.x * blockDim.x + threadIdx.x;
    if (i < n) {
        float x = logits[i];
        float s;
        if (x >= 0.0f) { float e = expf(-x); s = 1.0f / (1.0f + e); }
        else           { float e = expf(x);  s = e / (1.0f + e); }
        cls[i] = __fsub_rn(1.0f, s);
    }
}

// One block per (b, q): 512 threads each produce C[b][q][t].
__global__ void c_kernel(const float* __restrict__ pred_points,
                         const float* __restrict__ tgt_points,
                         const float* __restrict__ cls,
                         float* __restrict__ C) {
    int bq = blockIdx.x;          // b*NQ + q
    int b  = bq >> 13;            // NQ = 8192
    int t  = threadIdx.x;
    float qx = pred_points[bq * 2 + 0];
    float qy = pred_points[bq * 2 + 1];
    float cl = cls[bq];
    float tx = tgt_points[(b * NT + t) * 2 + 0];
    float ty = tgt_points[(b * NT + t) * 2 + 1];
    C[(size_t)bq * NT + t] = cost_f32(qx, qy, cl, tx, ty);
}

// One wave per (b, target-row): argmin over 8192 columns of the f32 cost.
__global__ __launch_bounds__(256) void rowmin_kernel(
    const float* __restrict__ pred_points,
    const float* __restrict__ tgt_points,
    const float* __restrict__ cls,
    float* __restrict__ u0, int* __restrict__ jm) {
    const int wid  = blockIdx.x * 4 + (threadIdx.x >> 6);   // 4096 waves
    const int lane = threadIdx.x & 63;
    const int b = wid >> 9;
    const int i = wid & (NT - 1);
    const float tx = tgt_points[(b * NT + i) * 2 + 0];
    const float ty = tgt_points[(b * NT + i) * 2 + 1];
    const float2* p2 = (const float2*)pred_points;

    float best = DINF;
    int bestc = NQ;
    for (int k = 0; k < NQ / 64; ++k) {
        int c = k * 64 + lane;
        float2 q = p2[b * NQ + c];
        float cf = cost_f32(q.x, q.y, cls[b * NQ + c], tx, ty);
        if (cf < best) { best = cf; bestc = c; }   // ascending c -> first-min
    }
    for (int off = 32; off > 0; off >>= 1) {
        float ov = __shfl_down(best, off, 64);
        int   oc = __shfl_down(bestc, off, 64);
        if (ov < best || (ov == best && oc < bestc)) { best = ov; bestc = oc; }
    }
    if (lane == 0) { u0[b * NT + i] = best; jm[b * NT + i] = bestc; }
}

// Exact LSA: greedy (row-reduction) warm start -> JV augmenting-row-reduction
// (ARR) -> shortest-augmenting-path for any leftovers. One block per batch.
// Thread `tid` owns columns c = j*NTHR + tid.
__global__ __launch_bounds__(NTHR, 2) void lsa_kernel(
    const float* __restrict__ pred_points,
    const float* __restrict__ tgt_points,
    const float* __restrict__ cls,
    const float* __restrict__ u0,
    const int* __restrict__ jm,
    float* __restrict__ out_rows,
    float* __restrict__ out_cols) {
    const int b = blockIdx.x;
    const int tid = threadIdx.x;

    __shared__ short  path_s[NQ];      // 16 KB
    __shared__ short  row4col_s[NQ];   // 16 KB
    __shared__ short  col4row_s[NT];   // 1 KB
    __shared__ double u_s[NT];         // 4 KB
    __shared__ float  tg[NT * 2];      // 4 KB
    __shared__ short  jm_s[NT];        // 1 KB
    __shared__ short  dflag[NT];       // 1 KB
    __shared__ short  queue_s[QCAP];   // 5 KB: deferred rows + kicked rows
    __shared__ double l_minv[MAXL];    // SAP removal list
    __shared__ double l_v[MAXL];
    __shared__ short  l_k[MAXL];
    __shared__ short  l_r[MAXL];
    __shared__ unsigned long long p_k[2][NW];   // SAP partials (parity-buffered)
    __shared__ unsigned long long a_k1[NW];     // ARR partials
    __shared__ unsigned long long a_m2[NW];
    __shared__ int s_head, s_tail;

    for (int c = tid; c < NQ; c += NTHR) row4col_s[c] = -1;
    for (int r = tid; r < NT; r += NTHR) {
        col4row_s[r] = -1;
        u_s[r] = (double)u0[b * NT + r];
        jm_s[r] = (short)jm[b * NT + r];
    }
    for (int t = tid; t < NT * 2; t += NTHR) tg[t] = tgt_points[b * NT * 2 + t];

    // per-thread column state in registers (all indices compile-time)
    float  qx[CHUNKS], qy[CHUNKS], cl[CHUNKS];
    double vv[CHUNKS], sh[CHUNKS];
#pragma unroll
    for (int j = 0; j < CHUNKS; ++j) {
        int c = j * NTHR + tid;
        qx[j] = pred_points[(b * NQ + c) * 2 + 0];
        qy[j] = pred_points[(b * NQ + c) * 2 + 1];
        cl[j] = cls[b * NQ + c];
        vv[j] = 0.0;
    }
    __syncthreads();

    // ---- parallel greedy: row r assigned to jm[r] iff no earlier row claims it
    {
        const int r = tid;                 // NT == NTHR
        const short jmr = jm_s[r];
        int conflict = 0;
        for (int r2 = 0; r2 < r; ++r2) conflict |= (jm_s[r2] == jmr) ? 1 : 0;
        dflag[r] = (short)conflict;
        if (!conflict) { col4row_s[r] = jmr; row4col_s[jmr] = (short)r; }
        __syncthreads();
        int rank = 0;
        for (int r2 = 0; r2 < r; ++r2) rank += dflag[r2];
        if (conflict) queue_s[rank] = (short)r;
        if (r == NT - 1) { s_tail = rank + conflict; s_head = 0; }
        __syncthreads();
    }

    // ---- ARR: per unassigned row, find (min1,j1,min2) of c - v; u[i]=min2,
    // v[j1] -= (min2-min1); assign i->j1, kicking the previous owner.
    {
        int steps = 0;
        for (;;) {
            const int head = s_head, tail = s_tail;
            if (head >= tail || steps >= ARR_CAP) break;
            const int i = queue_s[head];
            const float tx = tg[i * 2 + 0];
            const float ty = tg[i * 2 + 1];

            double m1 = DINF, m2 = DINF;
            int c1 = NQ;
#pragma unroll
            for (int j = 0; j < CHUNKS; ++j) {
                float  cf = cost_f32(qx[j], qy[j], cl[j], tx, ty);
                double r  = (double)cf - vv[j];
                sh[j] = r;                               // exact, for owner
                if (r < m1)      { m2 = m1; m1 = r; c1 = j * NTHR + tid; }
                else if (r < m2) { m2 = r; }
            }
            unsigned long long k1  = pack_key(m1, c1);
            unsigned long long m2b = pack_key(m2, 0);    // value bits only
            for (int off = 32; off > 0; off >>= 1) {
                unsigned long long ok1 = __shfl_down(k1, off, 64);
                unsigned long long om2 = __shfl_down(m2b, off, 64);
                unsigned long long lo  = (ok1 < k1) ? ok1 : k1;
                unsigned long long hiv = ((ok1 < k1) ? k1 : ok1) & KMASK;
                k1 = lo;
                if (om2 < m2b) m2b = om2;
                if (hiv < m2b) m2b = hiv;
            }
            if ((tid & 63) == 0) { a_k1[tid >> 6] = k1; a_m2[tid >> 6] = m2b; }
            __syncthreads();
            k1  = a_k1[tid & (NW - 1)];
            m2b = a_m2[tid & (NW - 1)];
            for (int m = NW >> 1; m > 0; m >>= 1) {
                unsigned long long ok1 = __shfl_xor(k1, m, 64);
                unsigned long long om2 = __shfl_xor(m2b, m, 64);
                unsigned long long lo  = (ok1 < k1) ? ok1 : k1;
                unsigned long long hiv = ((ok1 < k1) ? k1 : ok1) & KMASK;
                k1 = lo;
                if (om2 < m2b) m2b = om2;
                if (hiv < m2b) m2b = hiv;
            }
            const int    j1  = (int)(k1 & 0x1FFFull);
            const double m2d = key_val(m2b);
            if ((j1 & (NTHR - 1)) == tid) {              // owner adjusts v[j1]
                const int slot = j1 >> 9;                // log2(NTHR)
#pragma unroll
                for (int j = 0; j < CHUNKS; ++j)
                    if (j == slot) vv[j] -= fmax(0.0, m2d - sh[j]);
            }
            if (tid == 0) {
                u_s[i] = m2d;
                const int ko = row4col_s[j1];
                row4col_s[j1] = (short)i;
                col4row_s[i]  = (short)j1;
                int t2 = tail;
                if (ko >= 0) { col4row_s[ko] = -1; queue_s[t2++] = (short)ko; }
                s_tail = t2;
                s_head = head + 1;
            }
            ++steps;
            __syncthreads();
        }
    }

    // ---- SAP for leftovers (ARR cap hit); exact, handles any feasible duals.
    const int lh = s_head, lt = s_tail;
    for (int di = lh; di < lt; ++di) {
        const int cur_row = queue_s[di];
#pragma unroll
        for (int j = 0; j < CHUNKS; ++j) sh[j] = DINF;
        int    i    = cur_row;
        double minv = 0.0;
        int    len  = 0;
        int    sink = -1;

        for (;;) {
            const double w  = minv - u_s[i];
            const float  tx = tg[i * 2 + 0];
            const float  ty = tg[i * 2 + 1];

            double best = DINF;
            int bestc = NQ;
#pragma unroll
            for (int j = 0; j < CHUNKS; ++j) {
                float  cf = cost_f32(qx[j], qy[j], cl[j], tx, ty);
                double rr = (w + (double)cf) - vv[j];
                if (rr < sh[j]) { sh[j] = rr; path_s[j * NTHR + tid] = (short)i; }
                if (sh[j] < best) { best = sh[j]; bestc = j * NTHR + tid; }
            }
            unsigned long long bkey = pack_key(best, bestc);
            for (int off = 32; off > 0; off >>= 1) {
                unsigned long long ok = __shfl_down(bkey, off, 64);
                if (ok < bkey) bkey = ok;
            }
            const int par = len & 1;
            if ((tid & 63) == 0) p_k[par][tid >> 6] = bkey;
            __syncthreads();
            bkey = p_k[par][tid & (NW - 1)];
            for (int m = NW >> 1; m > 0; m >>= 1) {
                unsigned long long ok = __shfl_xor(bkey, m, 64);
                if (ok < bkey) bkey = ok;
            }
            minv = key_val(bkey);
            const int k  = (int)(bkey & 0x1FFFull);
            const int rk = row4col_s[k];
            if ((k & (NTHR - 1)) == tid) {   // owner neutralizes its column
                const int jj = k >> 9;
#pragma unroll
                for (int j = 0; j < CHUNKS; ++j)
                    if (j == jj) { l_v[len] = vv[j]; vv[j] = -DINF; sh[j] = DINF; }
            }
            if (tid == 0) { l_k[len] = (short)k; l_minv[len] = minv; l_r[len] = (short)rk; }
            ++len;
            if (rk < 0) { sink = k; break; }
            i = rk;
        }
        __syncthreads();   // l_* / path_s writes visible to everyone

        const int L = len;
        for (int e = tid; e < L; e += NTHR) {
            int rk2 = l_r[e];
            if (rk2 >= 0) u_s[rk2] += minv - l_minv[e];
        }
        if (tid == 0) u_s[cur_row] += minv;
        for (int e = 0; e < L; ++e) {
            int k2 = l_k[e];
            if ((k2 & (NTHR - 1)) == tid) {
                const int jj = k2 >> 9;
                double nv = l_v[e] - (minv - l_minv[e]);
#pragma unroll
                for (int j = 0; j < CHUNKS; ++j)
                    if (j == jj) vv[j] = nv;
            }
        }
        if (tid == 0) {   // augment along the alternating path
            int j = sink;
            for (;;) {
                int ii = path_s[j];
                row4col_s[j] = (short)ii;
                int t = col4row_s[ii];
                col4row_s[ii] = (short)j;
                j = t;
                if (ii == cur_row) break;
            }
        }
        __syncthreads();
    }

    // row_ind = sorted(col4row), col_ind = argsort(col4row); values distinct
    for (int r = tid; r < NT; r += NTHR) {
        int q = col4row_s[r];
        int rank = 0;
        for (int r2 = 0; r2 < NT; ++r2) rank += (col4row_s[r2] < q) ? 1 : 0;
        out_rows[b * NT + rank] = (float)q;
        out_cols[b * NT + rank] = (float)r;
    }
}

extern "C" void kernel_launch(void* const* d_in, const int* in_sizes, int n_in,
                              void* d_out, int out_size, void* d_ws, size_t ws_size,
                              hipStream_t stream) {
    const float* logits = (const float*)d_in[0];  // (8, 8192, 1)
    const float* pred   = (const float*)d_in[1];  // (8, 8192, 2)
    const float* tgt    = (const float*)d_in[2];  // (8, 512, 2)

    float* out  = (float*)d_out;
    float* C    = out;                                   // BS*NQ*NT
    float* orow = out + (size_t)BS * NQ * NT;            // BS*NT
    float* ocol = orow + (size_t)BS * NT;                // BS*NT

    float* cls = (float*)d_ws;                           // BS*NQ floats
    float* u0  = cls + BS * NQ;                          // BS*NT floats
    int*   jmn = (int*)(u0 + BS * NT);                   // BS*NT ints

    cls_kernel<<<(BS * NQ + 255) / 256, 256, 0, stream>>>(logits, cls, BS * NQ);
    c_kernel<<<BS * NQ, NT, 0, stream>>>(pred, tgt, cls, C);
    rowmin_kernel<<<BS * NT / 4, 256, 0, stream>>>(pred, tgt, cls, u0, jmn);
    lsa_kernel<<<BS, NTHR, 0, stream>>>(pred, tgt, cls, u0, jmn, orow, ocol);
}

// Round 7
// 249.247 us; speedup vs baseline: 23.5575x; 1.2088x over previous
//
#include <hip/hip_runtime.h>
#include <math.h>

#define BS 8
#define NQ 8192
#define NT 512
#define NTHR 512
#define CHUNKS 16            // NQ / NTHR columns per thread
#define NW (NTHR / 64)       // 8 waves
#define MAXL (NT + 1)
#define QCAP 2560            // queue capacity (shorts)
#define KMASK 0xFFFFFFFFFFFFE000ull

#define DINF (__builtin_inf())

// f32 cost, FMA-contraction-free, bit-identical everywhere it is computed.
// Mirrors: dists = sqrt(dx*dx + dy*dy); C = 0.5f*dists + cls
__device__ __forceinline__ float cost_f32(float qx, float qy, float cl, float tx, float ty) {
    float dx = __fsub_rn(qx, tx);
    float dy = __fsub_rn(qy, ty);
    float d2 = __fadd_rn(__fmul_rn(dx, dx), __fmul_rn(dy, dy));
    float d  = __fsqrt_rn(d2);
    return __fadd_rn(__fmul_rn(0.5f, d), cl);
}

// packed (value,idx) key: non-negative doubles compare correctly as u64 bits;
// low 13 bits replaced by column idx -> min == (min value, lowest idx).
__device__ __forceinline__ unsigned long long pack_key(double v, int idx) {
    double c = fmax(v, 0.0);
    return (((unsigned long long)__double_as_longlong(c)) & KMASK)
         | (unsigned long long)((unsigned)idx & 0x1FFFu);
}
__device__ __forceinline__ double key_val(unsigned long long k) {
    return __longlong_as_double((long long)(k & KMASK));
}

__global__ void cls_kernel(const float* __restrict__ logits, float* __restrict__ cls, int n) {
    int i = blockIdx.x * blockDim.x + threadIdx.x;
    if (i < n) {
        float x = logits[i];
        float s;
        if (x >= 0.0f) { float e = expf(-x); s = 1.0f / (1.0f + e); }
        else           { float e = expf(x);  s = e / (1.0f + e); }
        cls[i] = __fsub_rn(1.0f, s);
    }
}

// One wave per (b, target-row): argmin over 8192 columns of the f32 cost.
__global__ __launch_bounds__(256) void rowmin_kernel(
    const float* __restrict__ pred_points,
    const float* __restrict__ tgt_points,
    const float* __restrict__ cls,
    float* __restrict__ u0, int* __restrict__ jm) {
    const int wid  = blockIdx.x * 4 + (threadIdx.x >> 6);   // 4096 waves
    const int lane = threadIdx.x & 63;
    const int b = wid >> 9;
    const int i = wid & (NT - 1);
    const float tx = tgt_points[(b * NT + i) * 2 + 0];
    const float ty = tgt_points[(b * NT + i) * 2 + 1];
    const float2* p2 = (const float2*)pred_points;

    float best = DINF;
    int bestc = NQ;
    for (int k = 0; k < NQ / 64; ++k) {
        int c = k * 64 + lane;
        float2 q = p2[b * NQ + c];
        float cf = cost_f32(q.x, q.y, cls[b * NQ + c], tx, ty);
        if (cf < best) { best = cf; bestc = c; }   // ascending c -> first-min
    }
    for (int off = 32; off > 0; off >>= 1) {
        float ov = __shfl_down(best, off, 64);
        int   oc = __shfl_down(bestc, off, 64);
        if (ov < best || (ov == best && oc < bestc)) { best = ov; bestc = oc; }
    }
    if (lane == 0) { u0[b * NT + i] = best; jm[b * NT + i] = bestc; }
}

// Fused kernel: blocks [0, BS) run the exact LSA solver (one block per batch);
// blocks [BS, BS + BS*NQ/4) fill the C matrix (4 queries x 512 targets each,
// float4 stores). The two halves are independent -> C fill hides under LSA.
__global__ __launch_bounds__(NTHR, 2) void fused_kernel(
    const float* __restrict__ pred_points,
    const float* __restrict__ tgt_points,
    const float* __restrict__ cls,
    const float* __restrict__ u0,
    const int* __restrict__ jm,
    float* __restrict__ C,
    float* __restrict__ out_rows,
    float* __restrict__ out_cols) {
    const int tid = threadIdx.x;

    // ---------------- C-fill branch ----------------
    if (blockIdx.x >= BS) {
        const int idx = blockIdx.x - BS;            // 0 .. BS*NQ/4-1
        const int bq  = idx * 4 + (tid >> 7);       // 4 queries per block
        const int b   = bq >> 13;
        const int t4  = (tid & 127) << 2;           // target 0..508 step 4
        const float2 q = ((const float2*)pred_points)[bq];
        const float cl = cls[bq];
        const float4* T4 = (const float4*)(tgt_points + b * NT * 2);
        const float4 f0 = T4[t4 >> 1];
        const float4 f1 = T4[(t4 >> 1) + 1];
        float4 r;
        r.x = cost_f32(q.x, q.y, cl, f0.x, f0.y);
        r.y = cost_f32(q.x, q.y, cl, f0.z, f0.w);
        r.z = cost_f32(q.x, q.y, cl, f1.x, f1.y);
        r.w = cost_f32(q.x, q.y, cl, f1.z, f1.w);
        ((float4*)(C + (size_t)bq * NT))[t4 >> 2] = r;
        return;
    }

    // ---------------- LSA branch ----------------
    const int b = blockIdx.x;

    __shared__ short  path_s[NQ];      // 16 KB
    __shared__ short  row4col_s[NQ];   // 16 KB
    __shared__ short  col4row_s[NT];   // 1 KB
    __shared__ double u_s[NT];         // 4 KB
    __shared__ float  tg[NT * 2];      // 4 KB
    __shared__ short  jm_s[NT];        // 1 KB
    __shared__ short  dflag[NT];       // 1 KB
    __shared__ short  queue_s[QCAP];   // 5 KB: deferred + kicked rows
    __shared__ double l_minv[MAXL];    // SAP removal list
    __shared__ double l_v[MAXL];
    __shared__ short  l_k[MAXL];
    __shared__ short  l_r[MAXL];
    __shared__ unsigned long long p_k[2][NW];   // SAP partials (parity)
    __shared__ unsigned long long a_k1[NW];     // ARR partials (barrier-protected)
    __shared__ unsigned long long a_m2[NW];
    __shared__ int s_tail0;

    for (int c = tid; c < NQ; c += NTHR) row4col_s[c] = -1;
    for (int r = tid; r < NT; r += NTHR) {
        col4row_s[r] = -1;
        u_s[r] = (double)u0[b * NT + r];
        jm_s[r] = (short)jm[b * NT + r];
    }
    for (int t = tid; t < NT * 2; t += NTHR) tg[t] = tgt_points[b * NT * 2 + t];

    // per-thread column state in registers (all indices compile-time)
    float  qx[CHUNKS], qy[CHUNKS], cl[CHUNKS];
    double vv[CHUNKS], sh[CHUNKS];
#pragma unroll
    for (int j = 0; j < CHUNKS; ++j) {
        int c = j * NTHR + tid;
        qx[j] = pred_points[(b * NQ + c) * 2 + 0];
        qy[j] = pred_points[(b * NQ + c) * 2 + 1];
        cl[j] = cls[b * NQ + c];
        vv[j] = 0.0;
    }
    __syncthreads();

    // ---- parallel greedy: row r gets jm[r] iff no earlier row claims it
    {
        const int r = tid;                 // NT == NTHR
        const short jmr = jm_s[r];
        int conflict = 0;
        for (int r2 = 0; r2 < r; ++r2) conflict |= (jm_s[r2] == jmr) ? 1 : 0;
        dflag[r] = (short)conflict;
        if (!conflict) { col4row_s[r] = jmr; row4col_s[jmr] = (short)r; }
        __syncthreads();
        int rank = 0;
        for (int r2 = 0; r2 < r; ++r2) rank += dflag[r2];
        if (conflict) queue_s[rank] = (short)r;
        if (r == NT - 1) s_tail0 = rank + conflict;
        __syncthreads();
    }

    // ---- ARR (capped): per unassigned row find (min1,j1,min2) of c - v;
    // u[i]=min2, v[j1] -= (min2-min1); assign i->j1 kicking previous owner.
    // TWO barriers per step: B1 before reading reduce results + row4col_s,
    // B2 before any bookkeeping writes (prevents the R6 read/write race).
    int head = 0, tail = s_tail0, steps = 0;
    {
        const int arr_cap = 3 * tail + 32;
        while (head < tail && steps < arr_cap) {
            const int i = queue_s[head];   // own redundant write or >=1-barrier old
            const float tx = tg[i * 2 + 0];
            const float ty = tg[i * 2 + 1];

            double m1 = DINF, m2 = DINF;
            int c1 = NQ;
#pragma unroll
            for (int j = 0; j < CHUNKS; ++j) {
                float  cf = cost_f32(qx[j], qy[j], cl[j], tx, ty);
                double r  = (double)cf - vv[j];
                sh[j] = r;                               // exact, for owner
                if (r < m1)      { m2 = m1; m1 = r; c1 = j * NTHR + tid; }
                else if (r < m2) { m2 = r; }
            }
            unsigned long long k1  = pack_key(m1, c1);
            unsigned long long m2b = pack_key(m2, 0);
            for (int off = 32; off > 0; off >>= 1) {
                unsigned long long ok1 = __shfl_down(k1, off, 64);
                unsigned long long om2 = __shfl_down(m2b, off, 64);
                unsigned long long lo  = (ok1 < k1) ? ok1 : k1;
                unsigned long long hiv = ((ok1 < k1) ? k1 : ok1) & KMASK;
                k1 = lo;
                if (om2 < m2b) m2b = om2;
                if (hiv < m2b) m2b = hiv;
            }
            if ((tid & 63) == 0) { a_k1[tid >> 6] = k1; a_m2[tid >> 6] = m2b; }
            __syncthreads();                               // B1
            k1  = a_k1[tid & (NW - 1)];
            m2b = a_m2[tid & (NW - 1)];
            for (int m = NW >> 1; m > 0; m >>= 1) {
                unsigned long long ok1 = __shfl_xor(k1, m, 64);
                unsigned long long om2 = __shfl_xor(m2b, m, 64);
                unsigned long long lo  = (ok1 < k1) ? ok1 : k1;
                unsigned long long hiv = ((ok1 < k1) ? k1 : ok1) & KMASK;
                k1 = lo;
                if (om2 < m2b) m2b = om2;
                if (hiv < m2b) m2b = hiv;
            }
            const int    j1  = (int)(k1 & 0x1FFFull);
            const double m2d = key_val(m2b);
            const int    rk  = row4col_s[j1];              // read BEFORE B2
            __syncthreads();                               // B2
            // redundant bookkeeping: identical values from every thread
            row4col_s[j1] = (short)i;
            col4row_s[i]  = (short)j1;
            u_s[i]        = m2d;
            if (rk >= 0) { col4row_s[rk] = -1; queue_s[tail] = (short)rk; }
            if ((j1 & (NTHR - 1)) == tid) {     // owner adjusts v[j1]
                const int slot = j1 >> 9;       // log2(NTHR)
#pragma unroll
                for (int j = 0; j < CHUNKS; ++j)
                    if (j == slot) vv[j] -= fmax(0.0, m2d - sh[j]);
            }
            ++head; ++steps;
            if (rk >= 0) ++tail;
        }
    }
    __syncthreads();

    // ---- SAP for leftovers (exact; handles any feasible duals)
    for (int di = head; di < tail; ++di) {
        const int cur_row = queue_s[di];
#pragma unroll
        for (int j = 0; j < CHUNKS; ++j) sh[j] = DINF;
        int    i    = cur_row;
        double minv = 0.0;
        int    len  = 0;
        int    sink = -1;

        for (;;) {
            const double w  = minv - u_s[i];
            const float  tx = tg[i * 2 + 0];
            const float  ty = tg[i * 2 + 1];

            double best = DINF;
            int bestc = NQ;
#pragma unroll
            for (int j = 0; j < CHUNKS; ++j) {
                float  cf = cost_f32(qx[j], qy[j], cl[j], tx, ty);
                double rr = (w + (double)cf) - vv[j];
                if (rr < sh[j]) { sh[j] = rr; path_s[j * NTHR + tid] = (short)i; }
                if (sh[j] < best) { best = sh[j]; bestc = j * NTHR + tid; }
            }
            unsigned long long bkey = pack_key(best, bestc);
            for (int off = 32; off > 0; off >>= 1) {
                unsigned long long ok = __shfl_down(bkey, off, 64);
                if (ok < bkey) bkey = ok;
            }
            const int par = len & 1;
            if ((tid & 63) == 0) p_k[par][tid >> 6] = bkey;
            __syncthreads();
            bkey = p_k[par][tid & (NW - 1)];
            for (int m = NW >> 1; m > 0; m >>= 1) {
                unsigned long long ok = __shfl_xor(bkey, m, 64);
                if (ok < bkey) bkey = ok;
            }
            minv = key_val(bkey);
            const int k  = (int)(bkey & 0x1FFFull);
            const int rk = row4col_s[k];     // stable during Dijkstra: no writes
            if ((k & (NTHR - 1)) == tid) {   // owner neutralizes its column
                const int jj = k >> 9;
#pragma unroll
                for (int j = 0; j < CHUNKS; ++j)
                    if (j == jj) { l_v[len] = vv[j]; vv[j] = -DINF; sh[j] = DINF; }
            }
            if (tid == 0) { l_k[len] = (short)k; l_minv[len] = minv; l_r[len] = (short)rk; }
            ++len;
            if (rk < 0) { sink = k; break; }
            i = rk;
        }
        __syncthreads();   // l_* / path_s writes visible to everyone

        const int L = len;
        for (int e = tid; e < L; e += NTHR) {
            int rk2 = l_r[e];
            if (rk2 >= 0) u_s[rk2] += minv - l_minv[e];
        }
        if (tid == 0) u_s[cur_row] += minv;
        for (int e = 0; e < L; ++e) {
            int k2 = l_k[e];
            if ((k2 & (NTHR - 1)) == tid) {
                const int jj = k2 >> 9;
                double nv = l_v[e] - (minv - l_minv[e]);
#pragma unroll
                for (int j = 0; j < CHUNKS; ++j)
                    if (j == jj) vv[j] = nv;
            }
        }
        if (tid == 0) {   // augment along the alternating path
            int j = sink;
            for (;;) {
                int ii = path_s[j];
                row4col_s[j] = (short)ii;
                int t = col4row_s[ii];
                col4row_s[ii] = (short)j;
                j = t;
                if (ii == cur_row) break;
            }
        }
        __syncthreads();
    }

    // row_ind = sorted(col4row), col_ind = argsort(col4row); values distinct
    for (int r = tid; r < NT; r += NTHR) {
        int q = col4row_s[r];
        int rank = 0;
        for (int r2 = 0; r2 < NT; ++r2) rank += (col4row_s[r2] < q) ? 1 : 0;
        out_rows[b * NT + rank] = (float)q;
        out_cols[b * NT + rank] = (float)r;
    }
}

extern "C" void kernel_launch(void* const* d_in, const int* in_sizes, int n_in,
                              void* d_out, int out_size, void* d_ws, size_t ws_size,
                              hipStream_t stream) {
    const float* logits = (const float*)d_in[0];  // (8, 8192, 1)
    const float* pred   = (const float*)d_in[1];  // (8, 8192, 2)
    const float* tgt    = (const float*)d_in[2];  // (8, 512, 2)

    float* out  = (float*)d_out;
    float* C    = out;                                   // BS*NQ*NT
    float* orow = out + (size_t)BS * NQ * NT;            // BS*NT
    float* ocol = orow + (size_t)BS * NT;                // BS*NT

    float* cls = (float*)d_ws;                           // BS*NQ floats
    float* u0  = cls + BS * NQ;                          // BS*NT floats
    int*   jmn = (int*)(u0 + BS * NT);                   // BS*NT ints

    cls_kernel<<<(BS * NQ + 255) / 256, 256, 0, stream>>>(logits, cls, BS * NQ);
    rowmin_kernel<<<BS * NT / 4, 256, 0, stream>>>(pred, tgt, cls, u0, jmn);
    fused_kernel<<<BS + BS * NQ / 4, NTHR, 0, stream>>>(pred, tgt, cls, u0, jmn,
                                                        C, orow, ocol);
}

// Round 8
// 175.167 us; speedup vs baseline: 33.5201x; 1.4229x over previous
//
#include <hip/hip_runtime.h>
#include <math.h>

#define BS 8
#define NQ 8192
#define NT 512
#define NTHR 512
#define CHUNKS 16            // NQ / NTHR columns per thread (SAP scan)
#define NW (NTHR / 64)       // 8 waves
#define MAXL (NT + 2)
#define QCAP 4608            // ARR queue capacity (shorts)
#define NC 256               // candidates per row
#define KMASK 0xFFFFFFFFFFFFE000ull

#define DINF (__builtin_inf())

// f32 cost, FMA-contraction-free, bit-identical everywhere it is computed.
__device__ __forceinline__ float cost_f32(float qx, float qy, float cl, float tx, float ty) {
    float dx = __fsub_rn(qx, tx);
    float dy = __fsub_rn(qy, ty);
    float d2 = __fadd_rn(__fmul_rn(dx, dx), __fmul_rn(dy, dy));
    float d  = __fsqrt_rn(d2);
    return __fadd_rn(__fmul_rn(0.5f, d), cl);
}

// packed (value,idx) key: non-negative doubles compare as u64 bits;
// low 13 bits hold column idx -> min == (min value, lowest idx).
__device__ __forceinline__ unsigned long long pack_key(double v, int idx) {
    double c = fmax(v, 0.0);
    return (((unsigned long long)__double_as_longlong(c)) & KMASK)
         | (unsigned long long)((unsigned)idx & 0x1FFFu);
}
__device__ __forceinline__ double key_val(unsigned long long k) {
    return __longlong_as_double((long long)(k & KMASK));
}

__global__ void cls_kernel(const float* __restrict__ logits, float* __restrict__ cls, int n) {
    int i = blockIdx.x * blockDim.x + threadIdx.x;
    if (i < n) {
        float x = logits[i];
        float s;
        if (x >= 0.0f) { float e = expf(-x); s = 1.0f / (1.0f + e); }
        else           { float e = expf(x);  s = e / (1.0f + e); }
        cls[i] = __fsub_rn(1.0f, s);
    }
}

// One wave per (b,row): per-lane top-4 of the 128-column stride subset +
// 5th-smallest bound; also global (min,argmin) -> u0/jm.
// Candidate guarantee: any non-candidate column j has c[j] >= bnd.
__global__ __launch_bounds__(256) void cand_kernel(
    const float* __restrict__ pred_points,
    const float* __restrict__ tgt_points,
    const float* __restrict__ cls,
    float* __restrict__ u0, int* __restrict__ jm, float* __restrict__ bnd,
    float* __restrict__ ccost, unsigned short* __restrict__ cidx) {
    const int g    = blockIdx.x * 4 + (threadIdx.x >> 6);   // 0..4095
    const int lane = threadIdx.x & 63;
    const int b = g >> 9;
    const int i = g & (NT - 1);
    const float tx = tgt_points[(b * NT + i) * 2 + 0];
    const float ty = tgt_points[(b * NT + i) * 2 + 1];
    const float2* p2 = (const float2*)pred_points;

    float t0 = DINF, t1 = DINF, t2 = DINF, t3 = DINF, m5 = DINF;
    int   i0 = 0, i1 = 0, i2 = 0, i3 = 0;
    for (int k = 0; k < NQ / 64; ++k) {
        int c = k * 64 + lane;
        float2 q = p2[b * NQ + c];
        float cv = cost_f32(q.x, q.y, cls[b * NQ + c], tx, ty);
        if (cv < t3) {
            m5 = fminf(m5, t3);
            if (cv < t0)      { t3=t2;i3=i2; t2=t1;i2=i1; t1=t0;i1=i0; t0=cv;i0=c; }
            else if (cv < t1) { t3=t2;i3=i2; t2=t1;i2=i1; t1=cv;i1=c; }
            else if (cv < t2) { t3=t2;i3=i2; t2=cv;i2=c; }
            else              { t3=cv;i3=c; }
        } else m5 = fminf(m5, cv);
    }
    ((float4*)(ccost + ((size_t)g << 8)))[lane] = make_float4(t0, t1, t2, t3);
    ((ushort4*)(cidx + ((size_t)g << 8)))[lane] =
        make_ushort4((unsigned short)i0, (unsigned short)i1,
                     (unsigned short)i2, (unsigned short)i3);
    float bv = t0; int bc = i0; float bb = m5;
    for (int off = 32; off > 0; off >>= 1) {
        float ov = __shfl_down(bv, off, 64);
        int   oc = __shfl_down(bc, off, 64);
        float ob = __shfl_down(bb, off, 64);
        if (ov < bv || (ov == bv && oc < bc)) { bv = ov; bc = oc; }
        bb = fminf(bb, ob);
    }
    if (lane == 0) { u0[g] = bv; jm[g] = bc; bnd[g] = bb; }
}

// Fused: blocks [0,BS) = exact LSA (greedy -> single-wave candidate-ARR ->
// full-scan SAP); blocks [BS, BS+4096) fill C (16 queries x 512 targets).
__global__ __launch_bounds__(NTHR, 1) void fused_kernel(
    const float* __restrict__ pred_points,
    const float* __restrict__ tgt_points,
    const float* __restrict__ cls,
    const float* __restrict__ u0,
    const int* __restrict__ jm,
    const float* __restrict__ bnd,
    const float* __restrict__ ccost,
    const unsigned short* __restrict__ cidx,
    float* __restrict__ C,
    float* __restrict__ out_rows,
    float* __restrict__ out_cols) {
    const int tid = threadIdx.x;

    // ---------------- C-fill branch ----------------
    if (blockIdx.x >= BS) {
        const int idx2 = blockIdx.x - BS;           // 0..4095
        const int bq   = (idx2 << 4) + (tid >> 5);  // 16 queries per block
        const int b    = bq >> 13;
        const int g32  = tid & 31;
        const float2 q = ((const float2*)pred_points)[bq];
        const float cl = cls[bq];
        const float* tb = tgt_points + b * NT * 2;
#pragma unroll
        for (int s = 0; s < 4; ++s) {
            const int t = g32 * 4 + s * 128;
            float4 A  = *(const float4*)(tb + t * 2);
            float4 Bv = *(const float4*)(tb + t * 2 + 4);
            float4 r;
            r.x = cost_f32(q.x, q.y, cl, A.x,  A.y);
            r.y = cost_f32(q.x, q.y, cl, A.z,  A.w);
            r.z = cost_f32(q.x, q.y, cl, Bv.x, Bv.y);
            r.w = cost_f32(q.x, q.y, cl, Bv.z, Bv.w);
            *(float4*)(C + (size_t)bq * NT + t) = r;
        }
        return;
    }

    // ---------------- LSA branch ----------------
    const int b = blockIdx.x;
    extern __shared__ char smem[];
    double* v_s       = (double*)smem;                       // 8192
    double* u_s       = v_s + NQ;                            // 512
    double* l_minv    = u_s + NT;                            // MAXL
    double* l_v       = l_minv + MAXL;                       // MAXL
    unsigned long long* p_k = (unsigned long long*)(l_v + MAXL);  // NW
    float*  tg        = (float*)(p_k + NW);                  // 1024
    int*    s_int     = (int*)(tg + NT * 2);                 // 4
    short*  path_s    = (short*)(s_int + 4);                 // 8192
    short*  row4col_s = path_s + NQ;                         // 8192
    short*  col4row_s = row4col_s + NQ;                      // 512
    short*  jm_s      = col4row_s + NT;                      // 512
    short*  dflag     = jm_s + NT;                           // 512
    short*  sap_s     = dflag + NT;                          // 512
    short*  l_k       = sap_s + NT;                          // MAXL
    short*  l_r       = l_k + MAXL;                          // MAXL
    short*  queue_s   = l_r + MAXL;                          // QCAP

    for (int c = tid; c < NQ; c += NTHR) { row4col_s[c] = -1; v_s[c] = 0.0; }
    for (int r = tid; r < NT; r += NTHR) {
        col4row_s[r] = -1;
        u_s[r] = (double)u0[b * NT + r];
        jm_s[r] = (short)jm[b * NT + r];
    }
    for (int t = tid; t < NT * 2; t += NTHR) tg[t] = tgt_points[b * NT * 2 + t];

    // per-thread column state for SAP (registers)
    float  qx[CHUNKS], qy[CHUNKS], cl[CHUNKS];
    double sh[CHUNKS];
#pragma unroll
    for (int j = 0; j < CHUNKS; ++j) {
        int c = j * NTHR + tid;
        qx[j] = pred_points[(b * NQ + c) * 2 + 0];
        qy[j] = pred_points[(b * NQ + c) * 2 + 1];
        cl[j] = cls[b * NQ + c];
    }
    __syncthreads();

    // ---- parallel greedy: row r gets jm[r] iff no earlier row claims it
    {
        const int r = tid;
        const short jmr = jm_s[r];
        int conflict = 0;
        for (int r2 = 0; r2 < r; ++r2) conflict |= (jm_s[r2] == jmr) ? 1 : 0;
        dflag[r] = (short)conflict;
        if (!conflict) { col4row_s[r] = jmr; row4col_s[jmr] = (short)r; }
        __syncthreads();
        int rank = 0;
        for (int r2 = 0; r2 < r; ++r2) rank += dflag[r2];
        if (conflict) queue_s[rank] = (short)r;
        if (r == NT - 1) s_int[0] = rank + conflict;   // tail0
        __syncthreads();
    }

    // ---- single-wave candidate ARR (wave 0 only, no barriers inside)
    if (tid < 64) {
        const int lane = tid;
        int head = 0, tail = s_int[0], steps = 0, nsap = 0;
        const int cap0 = 8 * tail + 64;
        const int cap  = cap0 < (QCAP - NT - 8) ? cap0 : (QCAP - NT - 8);
        int pf_row = -1;
        float4 pf_c; ushort4 pf_i; float pf_b;
        while (head < tail && steps < cap) {
            const int i = queue_s[head];
            const int g = (b << 9) + i;
            float4 cc; ushort4 ci; float bb;
            if (pf_row == g) { cc = pf_c; ci = pf_i; bb = pf_b; }
            else {
                cc = ((const float4*)(ccost + ((size_t)g << 8)))[lane];
                ci = ((const ushort4*)(cidx + ((size_t)g << 8)))[lane];
                bb = bnd[g];
            }
            if (head + 1 < tail) {   // software prefetch next queued row
                const int ng = (b << 9) + queue_s[head + 1];
                pf_c = ((const float4*)(ccost + ((size_t)ng << 8)))[lane];
                pf_i = ((const ushort4*)(cidx + ((size_t)ng << 8)))[lane];
                pf_b = bnd[ng];
                pf_row = ng;
            } else pf_row = -1;

            const double rr0 = (double)cc.x - v_s[ci.x];
            const double rr1 = (double)cc.y - v_s[ci.y];
            const double rr2 = (double)cc.z - v_s[ci.z];
            const double rr3 = (double)cc.w - v_s[ci.w];
            const unsigned long long q0 = pack_key(rr0, ci.x);
            const unsigned long long q1 = pack_key(rr1, ci.y);
            const unsigned long long q2 = pack_key(rr2, ci.z);
            const unsigned long long q3 = pack_key(rr3, ci.w);
            unsigned long long ka = q0 < q1 ? q0 : q1, kb = q0 < q1 ? q1 : q0;
            unsigned long long kc = q2 < q3 ? q2 : q3, kd = q2 < q3 ? q3 : q2;
            unsigned long long k1  = ka < kc ? ka : kc;
            unsigned long long t2_ = ka < kc ? kc : ka;
            unsigned long long t3_ = kb < kd ? kb : kd;
            unsigned long long m2b = (t2_ < t3_ ? t2_ : t3_) & KMASK;
            for (int m = 32; m > 0; m >>= 1) {
                unsigned long long ok1 = __shfl_xor(k1, m, 64);
                unsigned long long om2 = __shfl_xor(m2b, m, 64);
                unsigned long long lo  = (ok1 < k1) ? ok1 : k1;
                unsigned long long hiv = ((ok1 < k1) ? k1 : ok1) & KMASK;
                k1 = lo;
                if (om2 < m2b) m2b = om2;
                if (hiv < m2b) m2b = hiv;
            }
            const int    j1  = (int)(k1 & 0x1FFFull);
            const double m2d = key_val(m2b);
            if (m2d < (double)bb) {   // candidate bound certified -> exact step
                const int rk = row4col_s[j1];   // uniform broadcast read
                // owner slot writes v[j1] = min(v_old, c - m2d)  (slack 0, no increase)
                if (q0 == k1) { double nv = (double)cc.x - m2d; if (nv < v_s[j1]) v_s[j1] = nv; }
                if (q1 == k1) { double nv = (double)cc.y - m2d; if (nv < v_s[j1]) v_s[j1] = nv; }
                if (q2 == k1) { double nv = (double)cc.z - m2d; if (nv < v_s[j1]) v_s[j1] = nv; }
                if (q3 == k1) { double nv = (double)cc.w - m2d; if (nv < v_s[j1]) v_s[j1] = nv; }
                if (lane == 0) {
                    row4col_s[j1] = (short)i;
                    col4row_s[i]  = (short)j1;
                    u_s[i]        = m2d;
                    if (rk >= 0) { col4row_s[rk] = -1; queue_s[tail] = (short)rk; }
                }
                if (rk >= 0) ++tail;
            } else {                   // bound failed -> exact SAP later
                if (lane == 0) sap_s[nsap] = (short)i;
                ++nsap;
            }
            ++head; ++steps;
        }
        if (lane == 0) { s_int[1] = head; s_int[2] = tail; s_int[3] = nsap; }
    }
    __syncthreads();

    // ---- SAP for leftovers (exact full scan, v in LDS)
    const int lhead = s_int[1], ltail = s_int[2], nsap = s_int[3];
    const int NL = nsap + (ltail - lhead);
    for (int di = 0; di < NL; ++di) {
        const int cur_row = (di < nsap) ? sap_s[di] : queue_s[lhead + di - nsap];
#pragma unroll
        for (int j = 0; j < CHUNKS; ++j) sh[j] = DINF;
        int    i    = cur_row;
        double minv = 0.0;
        int    len  = 0;
        int    sink = -1;

        for (;;) {
            const double w  = minv - u_s[i];
            const float  tx = tg[i * 2 + 0];
            const float  ty = tg[i * 2 + 1];

            double best = DINF;
            int bestc = NQ;
#pragma unroll
            for (int j = 0; j < CHUNKS; ++j) {
                const int c = j * NTHR + tid;
                float  cf = cost_f32(qx[j], qy[j], cl[j], tx, ty);
                double rr = (w + (double)cf) - v_s[c];
                if (rr < sh[j]) { sh[j] = rr; path_s[c] = (short)i; }
                if (sh[j] < best) { best = sh[j]; bestc = c; }
            }
            unsigned long long bkey = pack_key(best, bestc);
            for (int off = 32; off > 0; off >>= 1) {
                unsigned long long ok = __shfl_down(bkey, off, 64);
                if (ok < bkey) bkey = ok;
            }
            if ((tid & 63) == 0) p_k[tid >> 6] = bkey;
            __syncthreads();                               // B1
            bkey = p_k[tid & (NW - 1)];
            for (int m = NW >> 1; m > 0; m >>= 1) {
                unsigned long long ok = __shfl_xor(bkey, m, 64);
                if (ok < bkey) bkey = ok;
            }
            minv = key_val(bkey);
            const int k  = (int)(bkey & 0x1FFFull);
            const int rk = row4col_s[k];     // stable during Dijkstra
            if (tid == 0) {
                l_v[len] = v_s[k]; v_s[k] = -DINF;   // neutralize column
                l_k[len] = (short)k; l_minv[len] = minv; l_r[len] = (short)rk;
            }
            if ((k & (NTHR - 1)) == tid) {   // owner freezes its sh register
                const int jj = k >> 9;
#pragma unroll
                for (int j = 0; j < CHUNKS; ++j)
                    if (j == jj) sh[j] = DINF;
            }
            __syncthreads();                               // B2
            ++len;
            if (rk < 0) { sink = k; break; }
            i = rk;
        }

        const int L = len;
        for (int e = tid; e < L; e += NTHR) {
            const int rk2 = l_r[e];
            if (rk2 >= 0) u_s[rk2] += minv - l_minv[e];
        }
        if (tid == 0) u_s[cur_row] += minv;
        for (int e = tid; e < L; e += NTHR)    // restore + v duals (distinct k)
            v_s[l_k[e]] = l_v[e] - (minv - l_minv[e]);
        __syncthreads();
        if (tid == 0) {   // augment along the alternating path
            int j = sink;
            for (;;) {
                const int ii = path_s[j];
                row4col_s[j] = (short)ii;
                const int t = col4row_s[ii];
                col4row_s[ii] = (short)j;
                j = t;
                if (ii == cur_row) break;
            }
        }
        __syncthreads();
    }

    // row_ind = sorted(col4row), col_ind = argsort(col4row); values distinct
    for (int r = tid; r < NT; r += NTHR) {
        const int q = col4row_s[r];
        int rank = 0;
        for (int r2 = 0; r2 < NT; ++r2) rank += (col4row_s[r2] < q) ? 1 : 0;
        out_rows[b * NT + rank] = (float)q;
        out_cols[b * NT + rank] = (float)r;
    }
}

extern "C" void kernel_launch(void* const* d_in, const int* in_sizes, int n_in,
                              void* d_out, int out_size, void* d_ws, size_t ws_size,
                              hipStream_t stream) {
    const float* logits = (const float*)d_in[0];  // (8, 8192, 1)
    const float* pred   = (const float*)d_in[1];  // (8, 8192, 2)
    const float* tgt    = (const float*)d_in[2];  // (8, 512, 2)

    float* out  = (float*)d_out;
    float* C    = out;                                   // BS*NQ*NT
    float* orow = out + (size_t)BS * NQ * NT;            // BS*NT
    float* ocol = orow + (size_t)BS * NT;                // BS*NT

    char*  ws    = (char*)d_ws;
    float* cls   = (float*)ws;                                  // 256 KB
    float* u0    = (float*)(ws + 262144);                       // 16 KB
    float* bndp  = (float*)(ws + 278528);                       // 16 KB
    int*   jmn   = (int*)(ws + 294912);                         // 16 KB
    float* ccost = (float*)(ws + 311296);                       // 4 MB
    unsigned short* cidx = (unsigned short*)(ws + 311296 + 4194304); // 2 MB

    const size_t smem = (size_t)(NQ * 8 + NT * 8 + MAXL * 16 + NW * 8 +
                                 NT * 8 + 16 + NQ * 4 + NT * 8 + MAXL * 4 +
                                 QCAP * 2 + 64);

    cls_kernel<<<(BS * NQ + 255) / 256, 256, 0, stream>>>(logits, cls, BS * NQ);
    cand_kernel<<<BS * NT / 4, 256, 0, stream>>>(pred, tgt, cls, u0, jmn, bndp,
                                                 ccost, cidx);
    fused_kernel<<<BS + BS * NQ / 16, NTHR, smem, stream>>>(
        pred, tgt, cls, u0, jmn, bndp, ccost, cidx, C, orow, ocol);
}

// Round 9
// 138.089 us; speedup vs baseline: 42.5206x; 1.2685x over previous
//
#include <hip/hip_runtime.h>
#include <math.h>

#define BS 8
#define NQ 8192
#define NT 512
#define NTHR 512
#define CHUNKS 16            // NQ / NTHR columns per thread (SAP scan)
#define NW (NTHR / 64)       // 8 waves
#define MAXL (NT + 2)
#define QCAP 4608            // ARR queue capacity (shorts)
#define KMASK 0xFFFFFFFFFFFFE000ull

#define DINF (__builtin_inf())

// f32 cost, FMA-contraction-free, bit-identical everywhere it is computed.
__device__ __forceinline__ float cost_f32(float qx, float qy, float cl, float tx, float ty) {
    float dx = __fsub_rn(qx, tx);
    float dy = __fsub_rn(qy, ty);
    float d2 = __fadd_rn(__fmul_rn(dx, dx), __fmul_rn(dy, dy));
    float d  = __fsqrt_rn(d2);
    return __fadd_rn(__fmul_rn(0.5f, d), cl);
}

// packed (value,idx) key: non-negative doubles compare as u64 bits;
// low 13 bits hold column idx -> min == (min value, lowest idx).
__device__ __forceinline__ unsigned long long pack_key(double v, int idx) {
    double c = fmax(v, 0.0);
    return (((unsigned long long)__double_as_longlong(c)) & KMASK)
         | (unsigned long long)((unsigned)idx & 0x1FFFu);
}
__device__ __forceinline__ double key_val(unsigned long long k) {
    return __longlong_as_double((long long)(k & KMASK));
}

__global__ void cls_kernel(const float* __restrict__ logits, float* __restrict__ cls, int n) {
    int i = blockIdx.x * blockDim.x + threadIdx.x;
    if (i < n) {
        float x = logits[i];
        float s;
        if (x >= 0.0f) { float e = expf(-x); s = 1.0f / (1.0f + e); }
        else           { float e = expf(x);  s = e / (1.0f + e); }
        cls[i] = __fsub_rn(1.0f, s);
    }
}

// One wave per (b,row): per-lane top-2 of the 128-col stride subset + exact
// per-lane 3rd-smallest m3; bound bnd = min over lanes m3 (any non-candidate
// column has raw cost >= bnd). Also global (min,argmin) -> u0/jm.
__global__ __launch_bounds__(256) void cand_kernel(
    const float* __restrict__ pred_points,
    const float* __restrict__ tgt_points,
    const float* __restrict__ cls,
    float* __restrict__ u0, int* __restrict__ jm, float* __restrict__ bnd,
    float* __restrict__ ccost, unsigned short* __restrict__ cidx) {
    const int g    = blockIdx.x * 4 + (threadIdx.x >> 6);   // 0..4095
    const int lane = threadIdx.x & 63;
    const int b = g >> 9;
    const int i = g & (NT - 1);
    const float tx = tgt_points[(b * NT + i) * 2 + 0];
    const float ty = tgt_points[(b * NT + i) * 2 + 1];
    const float2* p2 = (const float2*)pred_points;

    float t0 = DINF, t1 = DINF, m3 = DINF;
    int   i0 = 0, i1 = 0;
    for (int k = 0; k < NQ / 64; ++k) {
        int c = k * 64 + lane;
        float2 q = p2[b * NQ + c];
        float cv = cost_f32(q.x, q.y, cls[b * NQ + c], tx, ty);
        if (cv < t1) {
            m3 = t1;
            if (cv < t0) { t1 = t0; i1 = i0; t0 = cv; i0 = c; }
            else         { t1 = cv; i1 = c; }
        } else m3 = fminf(m3, cv);
    }
    ((float2*)(ccost + ((size_t)g << 7)))[lane] = make_float2(t0, t1);
    ((ushort2*)(cidx + ((size_t)g << 7)))[lane] =
        make_ushort2((unsigned short)i0, (unsigned short)i1);
    float bv = t0; int bc = i0; float bb = m3;
    for (int off = 32; off > 0; off >>= 1) {
        float ov = __shfl_down(bv, off, 64);
        int   oc = __shfl_down(bc, off, 64);
        float ob = __shfl_down(bb, off, 64);
        if (ov < bv || (ov == bv && oc < bc)) { bv = ov; bc = oc; }
        bb = fminf(bb, ob);
    }
    if (lane == 0) { u0[g] = bv; jm[g] = bc; bnd[g] = bb; }
}

// Fused: blocks [0,BS) = exact LSA (greedy -> 8-way parallel-round auction ->
// full-scan SAP); blocks [BS, BS+4096) fill C (16 queries x 512 targets).
__global__ __launch_bounds__(NTHR, 1) void fused_kernel(
    const float* __restrict__ pred_points,
    const float* __restrict__ tgt_points,
    const float* __restrict__ cls,
    const float* __restrict__ u0,
    const int* __restrict__ jm,
    const float* __restrict__ bnd,
    const float* __restrict__ ccost,
    const unsigned short* __restrict__ cidx,
    float* __restrict__ C,
    float* __restrict__ out_rows,
    float* __restrict__ out_cols) {
    const int tid = threadIdx.x;

    // ---------------- C-fill branch ----------------
    if (blockIdx.x >= BS) {
        const int idx2 = blockIdx.x - BS;           // 0..4095
        const int bq   = (idx2 << 4) + (tid >> 5);  // 16 queries per block
        const int b    = bq >> 13;
        const int g32  = tid & 31;
        const float2 q = ((const float2*)pred_points)[bq];
        const float cl = cls[bq];
        const float* tb = tgt_points + b * NT * 2;
#pragma unroll
        for (int s = 0; s < 4; ++s) {
            const int t = g32 * 4 + s * 128;
            float4 A  = *(const float4*)(tb + t * 2);
            float4 Bv = *(const float4*)(tb + t * 2 + 4);
            float4 r;
            r.x = cost_f32(q.x, q.y, cl, A.x,  A.y);
            r.y = cost_f32(q.x, q.y, cl, A.z,  A.w);
            r.z = cost_f32(q.x, q.y, cl, Bv.x, Bv.y);
            r.w = cost_f32(q.x, q.y, cl, Bv.z, Bv.w);
            *(float4*)(C + (size_t)bq * NT + t) = r;
        }
        return;
    }

    // ---------------- LSA branch ----------------
    const int b = blockIdx.x;
    extern __shared__ char smem[];
    double* v_s       = (double*)smem;                       // 8192
    double* u_s       = v_s + NQ;                            // 512
    double* l_minv    = u_s + NT;                            // MAXL
    double* l_v       = l_minv + MAXL;                       // MAXL
    double* bid_m2    = l_v + MAXL;                          // 8
    unsigned long long* p_k = (unsigned long long*)(bid_m2 + 8);  // NW
    float*  tg        = (float*)(p_k + NW);                  // 1024
    float*  bnd_s     = tg + NT * 2;                         // 512
    float*  bid_c     = bnd_s + NT;                          // 8
    int*    s_int     = (int*)(bid_c + 8);                   // 4
    int*    bid_j     = s_int + 4;                           // 8
    short*  bid_row   = (short*)(bid_j + 8);                 // 8
    short*  path_s    = bid_row + 8;                         // 8192
    short*  row4col_s = path_s + NQ;                         // 8192
    short*  col4row_s = row4col_s + NQ;                      // 512
    short*  jm_s      = col4row_s + NT;                      // 512
    short*  dflag     = jm_s + NT;                           // 512
    short*  sap_s     = dflag + NT;                          // 512
    short*  l_k       = sap_s + NT;                          // MAXL
    short*  l_r       = l_k + MAXL;                          // MAXL
    short*  queue_s   = l_r + MAXL;                          // QCAP

    for (int c = tid; c < NQ; c += NTHR) { row4col_s[c] = -1; v_s[c] = 0.0; }
    for (int r = tid; r < NT; r += NTHR) {
        col4row_s[r] = -1;
        u_s[r]   = (double)u0[b * NT + r];
        jm_s[r]  = (short)jm[b * NT + r];
        bnd_s[r] = bnd[b * NT + r];
    }
    for (int t = tid; t < NT * 2; t += NTHR) tg[t] = tgt_points[b * NT * 2 + t];

    // per-thread column state for SAP (registers)
    float  qx[CHUNKS], qy[CHUNKS], cl[CHUNKS];
    double sh[CHUNKS];
#pragma unroll
    for (int j = 0; j < CHUNKS; ++j) {
        int c = j * NTHR + tid;
        qx[j] = pred_points[(b * NQ + c) * 2 + 0];
        qy[j] = pred_points[(b * NQ + c) * 2 + 1];
        cl[j] = cls[b * NQ + c];
    }
    __syncthreads();

    // ---- parallel greedy: row r gets jm[r] iff no earlier row claims it
    {
        const int r = tid;
        const short jmr = jm_s[r];
        int conflict = 0;
        for (int r2 = 0; r2 < r; ++r2) conflict |= (jm_s[r2] == jmr) ? 1 : 0;
        dflag[r] = (short)conflict;
        if (!conflict) { col4row_s[r] = jmr; row4col_s[jmr] = (short)r; }
        __syncthreads();
        int rank = 0;
        for (int r2 = 0; r2 < r; ++r2) rank += dflag[r2];
        if (conflict) queue_s[rank] = (short)r;
        if (r == NT - 1) s_int[0] = rank + conflict;   // tail0
        __syncthreads();
    }

    // ---- parallel-round auction: up to 8 rows bid per round (1 row/wave).
    // Exactness: all bids use the round-start v; each column commits <=1
    // winner; v only decreases; u[i]=m2, v[j1]=c-m2 => dual feasibility + CS
    // hold after every round (Jacobi auction). Losers/kicked requeue;
    // cert-failures (m2 >= bnd) go to the exact SAP finisher.
    int head = 0, tail = s_int[0], nsap = 0;
    {
        const int tail0 = tail;
        const int rcap = (tail0 + 64 < 256) ? tail0 + 64 : 256;
        const int w = tid >> 6, lane = tid & 63;
        int rounds = 0;
        while (head < tail && rounds < rcap) {
            const int nrows = (tail - head < NW) ? (tail - head) : NW;
            if (w < nrows) {
                const int row = queue_s[head + w];
                const int g = (b << 9) + row;
                const float2  cc = ((const float2*)(ccost + ((size_t)g << 7)))[lane];
                const ushort2 ci = ((const ushort2*)(cidx + ((size_t)g << 7)))[lane];
                const double rr0 = (double)cc.x - v_s[ci.x];
                const double rr1 = (double)cc.y - v_s[ci.y];
                const unsigned long long q0 = pack_key(rr0, ci.x);
                const unsigned long long q1 = pack_key(rr1, ci.y);
                unsigned long long k1  = q0 < q1 ? q0 : q1;
                unsigned long long m2b = (q0 < q1 ? q1 : q0) & KMASK;
                for (int m = 32; m > 0; m >>= 1) {
                    unsigned long long ok1 = __shfl_xor(k1, m, 64);
                    unsigned long long om2 = __shfl_xor(m2b, m, 64);
                    unsigned long long lo  = (ok1 < k1) ? ok1 : k1;
                    unsigned long long hiv = ((ok1 < k1) ? k1 : ok1) & KMASK;
                    k1 = lo;
                    if (om2 < m2b) m2b = om2;
                    if (hiv < m2b) m2b = hiv;
                }
                const double m2d = key_val(m2b);
                if (q0 == k1) bid_c[w] = cc.x;     // unique winner lane
                if (q1 == k1) bid_c[w] = cc.y;
                if (lane == 0) {
                    bid_row[w] = (short)row;
                    bid_m2[w]  = m2d;
                    bid_j[w]   = (m2d < (double)bnd_s[row]) ? (int)(k1 & 0x1FFFull) : -1;
                }
            }
            __syncthreads();
            if (tid == 0) {
                int cj[NW]; int nc = 0;
                int t2 = tail, ns = nsap;
                for (int e = 0; e < nrows; ++e) {
                    const int j1 = bid_j[e];
                    const int row = bid_row[e];
                    if (j1 < 0) { sap_s[ns++] = (short)row; continue; }
                    int dup = 0;
                    for (int x = 0; x < nc; ++x) dup |= (cj[x] == j1);
                    if (dup) { queue_s[t2++] = (short)row; continue; }   // loser
                    cj[nc++] = j1;
                    const double m2d = bid_m2[e];
                    const int ko = row4col_s[j1];
                    row4col_s[j1]  = (short)row;
                    col4row_s[row] = (short)j1;
                    u_s[row] = m2d;
                    const double nv = (double)bid_c[e] - m2d;
                    if (nv < v_s[j1]) v_s[j1] = nv;
                    if (ko >= 0) { col4row_s[ko] = -1; queue_s[t2++] = (short)ko; }
                }
                s_int[0] = head + nrows; s_int[1] = t2; s_int[2] = ns;
            }
            __syncthreads();
            head = s_int[0]; tail = s_int[1]; nsap = s_int[2];
            ++rounds;
        }
    }

    // ---- SAP for leftovers (exact full scan, v in LDS)
    const int NL = nsap + (tail - head);
    for (int di = 0; di < NL; ++di) {
        const int cur_row = (di < nsap) ? sap_s[di] : queue_s[head + di - nsap];
#pragma unroll
        for (int j = 0; j < CHUNKS; ++j) sh[j] = DINF;
        int    i    = cur_row;
        double minv = 0.0;
        int    len  = 0;
        int    sink = -1;

        for (;;) {
            const double w  = minv - u_s[i];
            const float  tx = tg[i * 2 + 0];
            const float  ty = tg[i * 2 + 1];

            double best = DINF;
            int bestc = NQ;
#pragma unroll
            for (int j = 0; j < CHUNKS; ++j) {
                const int c = j * NTHR + tid;
                float  cf = cost_f32(qx[j], qy[j], cl[j], tx, ty);
                double rr = (w + (double)cf) - v_s[c];
                if (rr < sh[j]) { sh[j] = rr; path_s[c] = (short)i; }
                if (sh[j] < best) { best = sh[j]; bestc = c; }
            }
            unsigned long long bkey = pack_key(best, bestc);
            for (int off = 32; off > 0; off >>= 1) {
                unsigned long long ok = __shfl_down(bkey, off, 64);
                if (ok < bkey) bkey = ok;
            }
            if ((tid & 63) == 0) p_k[tid >> 6] = bkey;
            __syncthreads();                               // B1
            bkey = p_k[tid & (NW - 1)];
            for (int m = NW >> 1; m > 0; m >>= 1) {
                unsigned long long ok = __shfl_xor(bkey, m, 64);
                if (ok < bkey) bkey = ok;
            }
            minv = key_val(bkey);
            const int k  = (int)(bkey & 0x1FFFull);
            const int rk = row4col_s[k];     // stable during Dijkstra
            if (tid == 0) {
                l_v[len] = v_s[k]; v_s[k] = -DINF;   // neutralize column
                l_k[len] = (short)k; l_minv[len] = minv; l_r[len] = (short)rk;
            }
            if ((k & (NTHR - 1)) == tid) {   // owner freezes its sh register
                const int jj = k >> 9;
#pragma unroll
                for (int j = 0; j < CHUNKS; ++j)
                    if (j == jj) sh[j] = DINF;
            }
            __syncthreads();                               // B2
            ++len;
            if (rk < 0) { sink = k; break; }
            i = rk;
        }

        const int L = len;
        for (int e = tid; e < L; e += NTHR) {
            const int rk2 = l_r[e];
            if (rk2 >= 0) u_s[rk2] += minv - l_minv[e];
        }
        if (tid == 0) u_s[cur_row] += minv;
        for (int e = tid; e < L; e += NTHR)    // restore + v duals (distinct k)
            v_s[l_k[e]] = l_v[e] - (minv - l_minv[e]);
        __syncthreads();
        if (tid == 0) {   // augment along the alternating path
            int j = sink;
            for (;;) {
                const int ii = path_s[j];
                row4col_s[j] = (short)ii;
                const int t = col4row_s[ii];
                col4row_s[ii] = (short)j;
                j = t;
                if (ii == cur_row) break;
            }
        }
        __syncthreads();
    }

    // row_ind = sorted(col4row), col_ind = argsort(col4row); values distinct
    for (int r = tid; r < NT; r += NTHR) {
        const int q = col4row_s[r];
        int rank = 0;
        for (int r2 = 0; r2 < NT; ++r2) rank += (col4row_s[r2] < q) ? 1 : 0;
        out_rows[b * NT + rank] = (float)q;
        out_cols[b * NT + rank] = (float)r;
    }
}

extern "C" void kernel_launch(void* const* d_in, const int* in_sizes, int n_in,
                              void* d_out, int out_size, void* d_ws, size_t ws_size,
                              hipStream_t stream) {
    const float* logits = (const float*)d_in[0];  // (8, 8192, 1)
    const float* pred   = (const float*)d_in[1];  // (8, 8192, 2)
    const float* tgt    = (const float*)d_in[2];  // (8, 512, 2)

    float* out  = (float*)d_out;
    float* C    = out;                                   // BS*NQ*NT
    float* orow = out + (size_t)BS * NQ * NT;            // BS*NT
    float* ocol = orow + (size_t)BS * NT;                // BS*NT

    char*  ws    = (char*)d_ws;
    float* cls   = (float*)ws;                                  // 256 KB
    float* u0    = (float*)(ws + 262144);                       // 16 KB
    float* bndp  = (float*)(ws + 278528);                       // 16 KB
    int*   jmn   = (int*)(ws + 294912);                         // 16 KB
    float* ccost = (float*)(ws + 311296);                       // 2 MB
    unsigned short* cidx = (unsigned short*)(ws + 311296 + 2097152); // 1 MB

    const size_t smem = 132480;

    cls_kernel<<<(BS * NQ + 255) / 256, 256, 0, stream>>>(logits, cls, BS * NQ);
    cand_kernel<<<BS * NT / 4, 256, 0, stream>>>(pred, tgt, cls, u0, jmn, bndp,
                                                 ccost, cidx);
    fused_kernel<<<BS + BS * NQ / 16, NTHR, smem, stream>>>(
        pred, tgt, cls, u0, jmn, bndp, ccost, cidx, C, orow, ocol);
}

// Round 11
// 117.281 us; speedup vs baseline: 50.0646x; 1.1774x over previous
//
#include <hip/hip_runtime.h>
#include <math.h>

#define BS 8
#define NQ 8192
#define NT 512
#define NTHR 512
#define CHUNKS 16            // NQ / NTHR columns per thread (SAP scan)
#define NW (NTHR / 64)       // 8 waves
#define MAXL (NT + 2)
#define QCAP 4608            // ARR queue capacity (shorts)
#define KMASK 0xFFFFFFFFFFFFE000ull
#define CFB 240              // persistent C-fill blocks

#define DINF (__builtin_inf())

typedef float vf4 __attribute__((ext_vector_type(4)));   // native vector for nontemporal store

// f32 cost, FMA-contraction-free, bit-identical everywhere it is computed.
__device__ __forceinline__ float cost_f32(float qx, float qy, float cl, float tx, float ty) {
    float dx = __fsub_rn(qx, tx);
    float dy = __fsub_rn(qy, ty);
    float d2 = __fadd_rn(__fmul_rn(dx, dx), __fmul_rn(dy, dy));
    float d  = __fsqrt_rn(d2);
    return __fadd_rn(__fmul_rn(0.5f, d), cl);
}

// packed (value,idx) key: non-negative doubles compare as u64 bits;
// low 13 bits hold column idx -> min == (min value, lowest idx).
__device__ __forceinline__ unsigned long long pack_key(double v, int idx) {
    double c = fmax(v, 0.0);
    return (((unsigned long long)__double_as_longlong(c)) & KMASK)
         | (unsigned long long)((unsigned)idx & 0x1FFFu);
}
__device__ __forceinline__ double key_val(unsigned long long k) {
    return __longlong_as_double((long long)(k & KMASK));
}

__global__ void cls_kernel(const float* __restrict__ logits, float* __restrict__ cls, int n) {
    int i = blockIdx.x * blockDim.x + threadIdx.x;
    if (i < n) {
        float x = logits[i];
        float s;
        if (x >= 0.0f) { float e = expf(-x); s = 1.0f / (1.0f + e); }
        else           { float e = expf(x);  s = e / (1.0f + e); }
        cls[i] = __fsub_rn(1.0f, s);
    }
}

// One wave per (b,row): two independent even/odd top-2 chains per lane
// (2 columns per iteration -> 2x ILP on the insertion chain), merged at the
// end with lowest-index tie-break. bnd = certified lower bound on every
// column NOT in the written candidate list. Also global (min,argmin)->u0/jm.
__global__ __launch_bounds__(256) void cand_kernel(
    const float* __restrict__ pred_points,
    const float* __restrict__ tgt_points,
    const float* __restrict__ cls,
    float* __restrict__ u0, int* __restrict__ jm, float* __restrict__ bnd,
    float* __restrict__ ccost, unsigned short* __restrict__ cidx) {
    const int g    = blockIdx.x * 4 + (threadIdx.x >> 6);   // 0..4095
    const int lane = threadIdx.x & 63;
    const int b = g >> 9;
    const int i = g & (NT - 1);
    const float tx = tgt_points[(b * NT + i) * 2 + 0];
    const float ty = tgt_points[(b * NT + i) * 2 + 1];
    const float4* p4   = (const float4*)pred_points;  // two points per load
    const float2* cls2 = (const float2*)cls;

    float a0 = DINF, a1 = DINF, am = DINF; int ai0 = 0, ai1 = 0;
    float b0 = DINF, b1 = DINF, bm = DINF; int bi0 = 0, bi1 = 0;
    for (int k = 0; k < NQ / 128; ++k) {     // 64 iters, 2 cols each
        const int c = k * 128 + 2 * lane;
        const float4 qq  = p4[(b * NQ + c) >> 1];
        const float2 cc2 = cls2[(b * NQ + c) >> 1];
        const float cva = cost_f32(qq.x, qq.y, cc2.x, tx, ty);
        const float cvb = cost_f32(qq.z, qq.w, cc2.y, tx, ty);
        if (cva < a1) { am = a1; if (cva < a0) { a1 = a0; ai1 = ai0; a0 = cva; ai0 = c; } else { a1 = cva; ai1 = c; } }
        else am = fminf(am, cva);
        if (cvb < b1) { bm = b1; if (cvb < b0) { b1 = b0; bi1 = bi0; b0 = cvb; bi0 = c + 1; } else { b1 = cvb; bi1 = c + 1; } }
        else bm = fminf(bm, cvb);
    }
    // merge two sorted pairs, exact lowest-index tie-break
    float t0v, t1v, s3v; int t0i, t1i;
    const bool bWins = (b0 < a0) || (b0 == a0 && bi0 < ai0);
    if (!bWins) {
        t0v = a0; t0i = ai0;
        const bool a1Wins = (a1 < b0) || (a1 == b0 && ai1 < bi0);
        if (a1Wins) { t1v = a1; t1i = ai1; s3v = b0; }
        else        { t1v = b0; t1i = bi0; s3v = fminf(a1, b1); }
    } else {
        t0v = b0; t0i = bi0;
        const bool b1Wins = (b1 < a0) || (b1 == a0 && bi1 < ai0);
        if (b1Wins) { t1v = b1; t1i = bi1; s3v = a0; }
        else        { t1v = a0; t1i = ai0; s3v = fminf(b1, a1); }
    }
    const float bb0 = fminf(fminf(am, bm), s3v);

    ((float2*)(ccost + ((size_t)g << 7)))[lane] = make_float2(t0v, t1v);
    ((ushort2*)(cidx + ((size_t)g << 7)))[lane] =
        make_ushort2((unsigned short)t0i, (unsigned short)t1i);
    float bv = t0v; int bc = t0i; float bb = bb0;
    for (int off = 32; off > 0; off >>= 1) {
        float ov = __shfl_down(bv, off, 64);
        int   oc = __shfl_down(bc, off, 64);
        float ob = __shfl_down(bb, off, 64);
        if (ov < bv || (ov == bv && oc < bc)) { bv = ov; bc = oc; }
        bb = fminf(bb, ob);
    }
    if (lane == 0) { u0[g] = bv; jm[g] = bc; bnd[g] = bb; }
}

// Fused: blocks [0,BS) = exact LSA (greedy -> 8-way parallel-round auction ->
// full-scan SAP); blocks [BS, BS+CFB) = persistent grid-stride C fill.
__global__ __launch_bounds__(NTHR, 1) void fused_kernel(
    const float* __restrict__ pred_points,
    const float* __restrict__ tgt_points,
    const float* __restrict__ cls,
    const float* __restrict__ u0,
    const int* __restrict__ jm,
    const float* __restrict__ bnd,
    const float* __restrict__ ccost,
    const unsigned short* __restrict__ cidx,
    float* __restrict__ C,
    float* __restrict__ out_rows,
    float* __restrict__ out_cols) {
    const int tid = threadIdx.x;

    // ---------------- persistent C-fill branch ----------------
    if (blockIdx.x >= BS) {
        const int cfid = blockIdx.x - BS;            // 0..CFB-1
        const int ngrp = BS * NQ / 16;               // 4096 groups of 16 queries
        const int g32  = tid & 31;
        for (int grp = cfid; grp < ngrp; grp += CFB) {
            const int bq = (grp << 4) + (tid >> 5);  // 16 queries per group
            const int b  = bq >> 13;
            const float2 q = ((const float2*)pred_points)[bq];
            const float cl = cls[bq];
            const float* tb = tgt_points + b * NT * 2;
#pragma unroll
            for (int s = 0; s < 4; ++s) {
                const int t = g32 * 4 + s * 128;
                float4 A  = *(const float4*)(tb + t * 2);
                float4 Bv = *(const float4*)(tb + t * 2 + 4);
                vf4 r;
                r.x = cost_f32(q.x, q.y, cl, A.x,  A.y);
                r.y = cost_f32(q.x, q.y, cl, A.z,  A.w);
                r.z = cost_f32(q.x, q.y, cl, Bv.x, Bv.y);
                r.w = cost_f32(q.x, q.y, cl, Bv.z, Bv.w);
                __builtin_nontemporal_store(r, (vf4*)(C + (size_t)bq * NT + t));
            }
        }
        return;
    }

    // ---------------- LSA branch ----------------
    const int b = blockIdx.x;
    extern __shared__ char smem[];
    double* v_s       = (double*)smem;                       // 8192
    double* u_s       = v_s + NQ;                            // 512
    double* l_minv    = u_s + NT;                            // MAXL
    double* l_v       = l_minv + MAXL;                       // MAXL
    double* bid_m2    = l_v + MAXL;                          // 8
    unsigned long long* p_k = (unsigned long long*)(bid_m2 + 8);  // NW
    float*  tg        = (float*)(p_k + NW);                  // 1024
    float*  bnd_s     = tg + NT * 2;                         // 512
    float*  bid_c     = bnd_s + NT;                          // 8
    int*    s_int     = (int*)(bid_c + 8);                   // 4
    int*    bid_j     = s_int + 4;                           // 8
    short*  bid_row   = (short*)(bid_j + 8);                 // 8
    short*  path_s    = bid_row + 8;                         // 8192
    short*  row4col_s = path_s + NQ;                         // 8192
    short*  col4row_s = row4col_s + NQ;                      // 512
    short*  jm_s      = col4row_s + NT;                      // 512
    short*  dflag     = jm_s + NT;                           // 512
    short*  sap_s     = dflag + NT;                          // 512
    short*  l_k       = sap_s + NT;                          // MAXL
    short*  l_r       = l_k + MAXL;                          // MAXL
    short*  queue_s   = l_r + MAXL;                          // QCAP

    for (int c = tid; c < NQ; c += NTHR) { row4col_s[c] = -1; v_s[c] = 0.0; }
    for (int r = tid; r < NT; r += NTHR) {
        col4row_s[r] = -1;
        u_s[r]   = (double)u0[b * NT + r];
        jm_s[r]  = (short)jm[b * NT + r];
        bnd_s[r] = bnd[b * NT + r];
    }
    for (int t = tid; t < NT * 2; t += NTHR) tg[t] = tgt_points[b * NT * 2 + t];

    // per-thread column state for SAP (registers)
    float  qx[CHUNKS], qy[CHUNKS], cl[CHUNKS];
    double sh[CHUNKS];
#pragma unroll
    for (int j = 0; j < CHUNKS; ++j) {
        int c = j * NTHR + tid;
        qx[j] = pred_points[(b * NQ + c) * 2 + 0];
        qy[j] = pred_points[(b * NQ + c) * 2 + 1];
        cl[j] = cls[b * NQ + c];
    }
    __syncthreads();

    // ---- parallel greedy: row r gets jm[r] iff no earlier row claims it
    {
        const int r = tid;
        const short jmr = jm_s[r];
        int conflict = 0;
        for (int r2 = 0; r2 < r; ++r2) conflict |= (jm_s[r2] == jmr) ? 1 : 0;
        dflag[r] = (short)conflict;
        if (!conflict) { col4row_s[r] = jmr; row4col_s[jmr] = (short)r; }
        __syncthreads();
        int rank = 0;
        for (int r2 = 0; r2 < r; ++r2) rank += dflag[r2];
        if (conflict) queue_s[rank] = (short)r;
        if (r == NT - 1) s_int[0] = rank + conflict;   // tail0
        __syncthreads();
    }

    // ---- parallel-round auction: up to 8 rows bid per round (1 row/wave).
    // Exactness: all bids use the round-start v; each column commits <=1
    // winner; v only decreases; u[i]=m2, v[j1]=c-m2 => dual feasibility + CS
    // hold after every round (Jacobi auction). Losers/kicked requeue;
    // cert-failures (m2 >= bnd) go to the exact SAP finisher.
    int head = 0, tail = s_int[0], nsap = 0;
    {
        const int tail0 = tail;
        const int rcap = (tail0 + 64 < 256) ? tail0 + 64 : 256;
        const int w = tid >> 6, lane = tid & 63;
        int rounds = 0;
        while (head < tail && rounds < rcap) {
            const int nrows = (tail - head < NW) ? (tail - head) : NW;
            if (w < nrows) {
                const int row = queue_s[head + w];
                const int g = (b << 9) + row;
                const float2  cc = ((const float2*)(ccost + ((size_t)g << 7)))[lane];
                const ushort2 ci = ((const ushort2*)(cidx + ((size_t)g << 7)))[lane];
                const double rr0 = (double)cc.x - v_s[ci.x];
                const double rr1 = (double)cc.y - v_s[ci.y];
                const unsigned long long q0 = pack_key(rr0, ci.x);
                const unsigned long long q1 = pack_key(rr1, ci.y);
                unsigned long long k1  = q0 < q1 ? q0 : q1;
                unsigned long long m2b = (q0 < q1 ? q1 : q0) & KMASK;
                for (int m = 32; m > 0; m >>= 1) {
                    unsigned long long ok1 = __shfl_xor(k1, m, 64);
                    unsigned long long om2 = __shfl_xor(m2b, m, 64);
                    unsigned long long lo  = (ok1 < k1) ? ok1 : k1;
                    unsigned long long hiv = ((ok1 < k1) ? k1 : ok1) & KMASK;
                    k1 = lo;
                    if (om2 < m2b) m2b = om2;
                    if (hiv < m2b) m2b = hiv;
                }
                const double m2d = key_val(m2b);
                if (q0 == k1) bid_c[w] = cc.x;     // unique winner lane
                if (q1 == k1) bid_c[w] = cc.y;
                if (lane == 0) {
                    bid_row[w] = (short)row;
                    bid_m2[w]  = m2d;
                    bid_j[w]   = (m2d < (double)bnd_s[row]) ? (int)(k1 & 0x1FFFull) : -1;
                }
            }
            __syncthreads();
            if (tid == 0) {
                int cj[NW]; int nc = 0;
                int t2 = tail, ns = nsap;
                for (int e = 0; e < nrows; ++e) {
                    const int j1 = bid_j[e];
                    const int row = bid_row[e];
                    if (j1 < 0) { sap_s[ns++] = (short)row; continue; }
                    int dup = 0;
                    for (int x = 0; x < nc; ++x) dup |= (cj[x] == j1);
                    if (dup) { queue_s[t2++] = (short)row; continue; }   // loser
                    cj[nc++] = j1;
                    const double m2d = bid_m2[e];
                    const int ko = row4col_s[j1];
                    row4col_s[j1]  = (short)row;
                    col4row_s[row] = (short)j1;
                    u_s[row] = m2d;
                    const double nv = (double)bid_c[e] - m2d;
                    if (nv < v_s[j1]) v_s[j1] = nv;
                    if (ko >= 0) { col4row_s[ko] = -1; queue_s[t2++] = (short)ko; }
                }
                s_int[0] = head + nrows; s_int[1] = t2; s_int[2] = ns;
            }
            __syncthreads();
            head = s_int[0]; tail = s_int[1]; nsap = s_int[2];
            ++rounds;
        }
    }

    // ---- SAP for leftovers (exact full scan, v in LDS)
    const int NL = nsap + (tail - head);
    for (int di = 0; di < NL; ++di) {
        const int cur_row = (di < nsap) ? sap_s[di] : queue_s[head + di - nsap];
#pragma unroll
        for (int j = 0; j < CHUNKS; ++j) sh[j] = DINF;
        int    i    = cur_row;
        double minv = 0.0;
        int    len  = 0;
        int    sink = -1;

        for (;;) {
            const double w  = minv - u_s[i];
            const float  tx = tg[i * 2 + 0];
            const float  ty = tg[i * 2 + 1];

            double best = DINF;
            int bestc = NQ;
#pragma unroll
            for (int j = 0; j < CHUNKS; ++j) {
                const int c = j * NTHR + tid;
                float  cf = cost_f32(qx[j], qy[j], cl[j], tx, ty);
                double rr = (w + (double)cf) - v_s[c];
                if (rr < sh[j]) { sh[j] = rr; path_s[c] = (short)i; }
                if (sh[j] < best) { best = sh[j]; bestc = c; }
            }
            unsigned long long bkey = pack_key(best, bestc);
            for (int off = 32; off > 0; off >>= 1) {
                unsigned long long ok = __shfl_down(bkey, off, 64);
                if (ok < bkey) bkey = ok;
            }
            if ((tid & 63) == 0) p_k[tid >> 6] = bkey;
            __syncthreads();                               // B1
            bkey = p_k[tid & (NW - 1)];
            for (int m = NW >> 1; m > 0; m >>= 1) {
                unsigned long long ok = __shfl_xor(bkey, m, 64);
                if (ok < bkey) bkey = ok;
            }
            minv = key_val(bkey);
            const int k  = (int)(bkey & 0x1FFFull);
            const int rk = row4col_s[k];     // stable during Dijkstra
            if (tid == 0) {
                l_v[len] = v_s[k]; v_s[k] = -DINF;   // neutralize column
                l_k[len] = (short)k; l_minv[len] = minv; l_r[len] = (short)rk;
            }
            if ((k & (NTHR - 1)) == tid) {   // owner freezes its sh register
                const int jj = k >> 9;
#pragma unroll
                for (int j = 0; j < CHUNKS; ++j)
                    if (j == jj) sh[j] = DINF;
            }
            __syncthreads();                               // B2
            ++len;
            if (rk < 0) { sink = k; break; }
            i = rk;
        }

        const int L = len;
        for (int e = tid; e < L; e += NTHR) {
            const int rk2 = l_r[e];
            if (rk2 >= 0) u_s[rk2] += minv - l_minv[e];
        }
        if (tid == 0) u_s[cur_row] += minv;
        for (int e = tid; e < L; e += NTHR)    // restore + v duals (distinct k)
            v_s[l_k[e]] = l_v[e] - (minv - l_minv[e]);
        __syncthreads();
        if (tid == 0) {   // augment along the alternating path
            int j = sink;
            for (;;) {
                const int ii = path_s[j];
                row4col_s[j] = (short)ii;
                const int t = col4row_s[ii];
                col4row_s[ii] = (short)j;
                j = t;
                if (ii == cur_row) break;
            }
        }
        __syncthreads();
    }

    // row_ind = sorted(col4row), col_ind = argsort(col4row); values distinct
    for (int r = tid; r < NT; r += NTHR) {
        const int q = col4row_s[r];
        int rank = 0;
        for (int r2 = 0; r2 < NT; ++r2) rank += (col4row_s[r2] < q) ? 1 : 0;
        out_rows[b * NT + rank] = (float)q;
        out_cols[b * NT + rank] = (float)r;
    }
}

extern "C" void kernel_launch(void* const* d_in, const int* in_sizes, int n_in,
                              void* d_out, int out_size, void* d_ws, size_t ws_size,
                              hipStream_t stream) {
    const float* logits = (const float*)d_in[0];  // (8, 8192, 1)
    const float* pred   = (const float*)d_in[1];  // (8, 8192, 2)
    const float* tgt    = (const float*)d_in[2];  // (8, 512, 2)

    float* out  = (float*)d_out;
    float* C    = out;                                   // BS*NQ*NT
    float* orow = out + (size_t)BS * NQ * NT;            // BS*NT
    float* ocol = orow + (size_t)BS * NT;                // BS*NT

    char*  ws    = (char*)d_ws;
    float* cls   = (float*)ws;                                  // 256 KB
    float* u0    = (float*)(ws + 262144);                       // 16 KB
    float* bndp  = (float*)(ws + 278528);                       // 16 KB
    int*   jmn   = (int*)(ws + 294912);                         // 16 KB
    float* ccost = (float*)(ws + 311296);                       // 2 MB
    unsigned short* cidx = (unsigned short*)(ws + 311296 + 2097152); // 1 MB

    const size_t smem = 132480;

    cls_kernel<<<(BS * NQ + 255) / 256, 256, 0, stream>>>(logits, cls, BS * NQ);
    cand_kernel<<<BS * NT / 4, 256, 0, stream>>>(pred, tgt, cls, u0, jmn, bndp,
                                                 ccost, cidx);
    fused_kernel<<<BS + CFB, NTHR, smem, stream>>>(
        pred, tgt, cls, u0, jmn, bndp, ccost, cidx, C, orow, ocol);
}